// Round 1
// baseline (1401.818 us; speedup 1.0000x reference)
//
#include <hip/hip_runtime.h>

typedef __bf16 bf16_t;
typedef __bf16 bf16x8 __attribute__((ext_vector_type(8)));
typedef float f32x4 __attribute__((ext_vector_type(4)));

// Problem constants
constexpr int Tn = 4 * 2048;   // tokens = B*S
constexpr int Dd = 1024;
constexpr int Ff = 4096;
constexpr int Oo = 1024;
constexpr int NEXP = 6;        // 2 shared + 4 routed

// flag-conditional scalar input load (inputs may be f32 or bf16; detected at runtime)
__device__ __forceinline__ float ldin(const void* p, size_t i, int isf32) {
    return isf32 ? ((const float*)p)[i] : (float)((const bf16_t*)p)[i];
}

// ---------------- dtype detector ----------------
__global__ void detect_kernel(const unsigned int* __restrict__ xw, int* __restrict__ flag) {
    __shared__ int cnt;
    if (threadIdx.x == 0) cnt = 0;
    __syncthreads();
    int c = 0;
    for (int i = threadIdx.x; i < 16384; i += 256) {
        unsigned w = xw[i];
        if (((w >> 7) & 0xFFu) == 0xFFu) ++c;
    }
    atomicAdd(&cnt, c);
    __syncthreads();
    if (threadIdx.x == 0) flag[0] = (cnt >= 4) ? 1 : 0;
}

// ---------------- x -> bf16 ----------------
__global__ void cvt_x_kernel(const void* __restrict__ x, const int* __restrict__ flag,
                             bf16_t* __restrict__ xb) {
    int f = flag[0];
    size_t i = (size_t)blockIdx.x * 256 + threadIdx.x;
    xb[i] = (bf16_t)ldin(x, i, f);
}

// ---------------- convert+transpose: src(+eofs) [R][C] -> bf16 dst [C][R] ----------------
__global__ void cvt_transpose_kernel(const void* __restrict__ src, size_t eofs,
                                     const int* __restrict__ flag,
                                     bf16_t* __restrict__ dst, int R, int C) {
    __shared__ bf16_t tile[32][33];
    int f = flag[0];
    int c0 = blockIdx.x * 32, r0 = blockIdx.y * 32;
    int tx = threadIdx.x, ty = threadIdx.y;
    #pragma unroll
    for (int i = 0; i < 32; i += 8)
        tile[ty + i][tx] = (bf16_t)ldin(src, eofs + (size_t)(r0 + ty + i) * C + c0 + tx, f);
    __syncthreads();
    #pragma unroll
    for (int i = 0; i < 32; i += 8)
        dst[(size_t)(c0 + ty + i) * R + r0 + tx] = tile[tx][ty + i];
}

// ---------------- gating ----------------
__global__ void gate_kernel(const void* __restrict__ x, const void* __restrict__ gw,
                            const void* __restrict__ gb, const int* __restrict__ flag,
                            float* __restrict__ coef) {
    int f = flag[0];
    int t = blockIdx.x;
    int lane = threadIdx.x;  // 64 threads
    float a0 = 0.f, a1 = 0.f, a2 = 0.f, a3 = 0.f;
    for (int d = lane; d < Dd; d += 64) {
        float xv = ldin(x, (size_t)t * Dd + d, f);
        a0 += xv * ldin(gw, (size_t)d * 4 + 0, f);
        a1 += xv * ldin(gw, (size_t)d * 4 + 1, f);
        a2 += xv * ldin(gw, (size_t)d * 4 + 2, f);
        a3 += xv * ldin(gw, (size_t)d * 4 + 3, f);
    }
    #pragma unroll
    for (int off = 32; off; off >>= 1) {
        a0 += __shfl_xor(a0, off);
        a1 += __shfl_xor(a1, off);
        a2 += __shfl_xor(a2, off);
        a3 += __shfl_xor(a3, off);
    }
    if (lane == 0) {
        float l[4] = {a0 + ldin(gb, 0, f), a1 + ldin(gb, 1, f),
                      a2 + ldin(gb, 2, f), a3 + ldin(gb, 3, f)};
        float mx = fmaxf(fmaxf(l[0], l[1]), fmaxf(l[2], l[3]));
        float e[4], s = 0.f;
        #pragma unroll
        for (int i = 0; i < 4; ++i) { e[i] = expf(l[i] - mx); s += e[i]; }
        float w[4];
        #pragma unroll
        for (int i = 0; i < 4; ++i) w[i] = e[i] / s;
        int i0 = 0;
        for (int i = 1; i < 4; ++i) if (w[i] > w[i0]) i0 = i;   // ties -> lowest idx
        int i1 = -1;
        for (int i = 0; i < 4; ++i) { if (i == i0) continue; if (i1 < 0 || w[i] > w[i1]) i1 = i; }
        float c[8] = {0.5f, 0.5f, 0.f, 0.f, 0.f, 0.f, 0.f, 0.f};
        c[2 + i0] = w[i0];
        c[2 + i1] = w[i1];
        float* dst = coef + (size_t)t * 8;
        #pragma unroll
        for (int k = 0; k < 8; ++k) dst[k] = c[k];
    }
}

// ---------------- acc init: acc[t][o] = sum_j coef[t][j]*b2[j][o] ----------------
__global__ void init_acc_kernel(const float* __restrict__ coef, const void* __restrict__ sb2,
                                const void* __restrict__ rb2, const int* __restrict__ flag,
                                float* __restrict__ acc) {
    int f = flag[0];
    size_t idx = (size_t)blockIdx.x * 256 + threadIdx.x;
    int t = (int)(idx >> 10);          // O = 1024
    int o = (int)(idx & 1023);
    const float* c = coef + (size_t)t * 8;
    float v = c[0] * ldin(sb2, o, f) + c[1] * ldin(sb2, Oo + o, f)
            + c[2] * ldin(rb2, o, f) + c[3] * ldin(rb2, Oo + o, f)
            + c[4] * ldin(rb2, 2 * Oo + o, f) + c[5] * ldin(rb2, 3 * Oo + o, f);
    acc[idx] = v;
}

// ---------------- final convert ----------------
__global__ void convert_kernel(const float* __restrict__ acc, const int* __restrict__ flag,
                               void* __restrict__ out) {
    int f = flag[0];
    size_t idx = (size_t)blockIdx.x * 256 + threadIdx.x;
    float v = acc[idx];
    if (v != v) v = 333.0f;   // NaN sentinel for diagnosis
    if (f) ((float*)out)[idx] = v;
    else   ((bf16_t*)out)[idx] = (bf16_t)v;
}

// ---------------- GEMM core: C = A[M,K] * Bt[N,K]^T ----------------
// 256xBN_ tile, BK=64, 512 threads = 8 waves (WM_ x WN_ wave grid).
// Deep-pipelined schedule (T3+T4+T5 from the technique catalog):
//   - double-buffered LDS K-tiles (2 x (A 32KB + B BN_/4 KB))
//   - stage(t+2) issued right after the barrier that ends all reads of buf[t&1]
//     (write-after-read safe), stays in flight ~1 full iteration
//   - counted s_waitcnt vmcnt(TOT) at the tile boundary (never drains to 0 in
//     the main loop) -> tile t+1 resident, tile t+2 still flying
//   - raw s_barrier + inline-asm waits + sched_barrier(0) fences (guide rule 18)
//   - s_setprio(1) around each MFMA cluster
// XOR bank-swizzle (as before): LDS slot (row, c8) holds global chunk c8 ^ (row&7);
// read at chunk (k8f ^ (r&7)). global_load_lds dst stays linear (wave-uniform+lane*16).
// XCD-aware bijective block swizzle (grid always a multiple of 8 here).
// MODE 1: obf = bf16( relu(acc + bias[b1_e+n]) * coef[m*8] );  MODE 2: oacc += acc
template <int MODE, int BN_, int WM_>
__launch_bounds__(512, 2)
__global__ void gemm_kernel(const bf16_t* __restrict__ A, const bf16_t* __restrict__ Bt,
                            int M, int N, int K,
                            const void* __restrict__ bias, size_t b1_e,
                            const int* __restrict__ flag,
                            const float* __restrict__ coef,
                            bf16_t* __restrict__ obf, float* __restrict__ oacc) {
    constexpr int BM = 256, BK = 64;
    constexpr int WN_ = 8 / WM_;
    constexpr int NI = 16 / WM_;          // i-frags (16 rows each) per wave
    constexpr int NJ = BN_ / (WN_ * 16);  // j-frags per wave
    constexpr int NIH = NI / 2;
    constexpr int NJH = NJ / 2;
    constexpr int ALOADS = 4;             // global_load_lds instrs per thread (A tile)
    constexpr int BLOADS = BN_ / 64;      // (B tile)
    constexpr int TOT = ALOADS + BLOADS;  // 8 (BN=256) or 6 (BN=128)

    __shared__ __align__(16) bf16_t Al[2][BM * BK];
    __shared__ __align__(16) bf16_t Bl[2][BN_ * BK];

    const int tid = threadIdx.x;
    const int lane = tid & 63;
    const int wave = tid >> 6;
    const int wm = wave / WN_;
    const int wn = wave % WN_;
    const int l15 = lane & 15;
    const int l4 = lane >> 4;
    const int r7 = l15 & 7;

    // XCD-aware bijective swizzle (nwg % 8 == 0 always: gridDim.y in {8,16})
    const int gx = gridDim.x;
    const int nwg = gx * gridDim.y;
    const int id = blockIdx.y * gx + blockIdx.x;
    const int cpx = nwg >> 3;
    const int sid = (id & 7) * cpx + (id >> 3);
    const int bm = (sid % gx) * BM;
    const int bn = (sid / gx) * BN_;

    const int nK = K / BK;

    auto stage = [&](int t, int b) {
        const int k0 = t * BK;
        #pragma unroll
        for (int it = 0; it < ALOADS; ++it) {
            int q = it * 512 + tid;
            int row = q >> 3, c8 = q & 7;
            int k8 = c8 ^ (row & 7);
            const bf16_t* g = A + (size_t)(bm + row) * K + k0 + k8 * 8;
            __builtin_amdgcn_global_load_lds(
                (const __attribute__((address_space(1))) unsigned int*)g,
                (__attribute__((address_space(3))) unsigned int*)(&Al[b][q * 8]), 16, 0, 0);
        }
        #pragma unroll
        for (int it = 0; it < BLOADS; ++it) {
            int q = it * 512 + tid;
            int row = q >> 3, c8 = q & 7;
            int k8 = c8 ^ (row & 7);
            const bf16_t* g = Bt + (size_t)(bn + row) * K + k0 + k8 * 8;
            __builtin_amdgcn_global_load_lds(
                (const __attribute__((address_space(1))) unsigned int*)g,
                (__attribute__((address_space(3))) unsigned int*)(&Bl[b][q * 8]), 16, 0, 0);
        }
    };

    f32x4 acc[NI][NJ] = {};

    // prologue: stage tiles 0 and 1; wait tile 0 only (counted)
    stage(0, 0);
    if (nK > 1) {
        stage(1, 1);
        if constexpr (TOT == 8) asm volatile("s_waitcnt vmcnt(8)" ::: "memory");
        else                    asm volatile("s_waitcnt vmcnt(6)" ::: "memory");
    } else {
        asm volatile("s_waitcnt vmcnt(0)" ::: "memory");
    }
    __builtin_amdgcn_sched_barrier(0);
    __builtin_amdgcn_s_barrier();
    __builtin_amdgcn_sched_barrier(0);

    const int a_off0 = ((l4 + 0) ^ r7) * 8;   // swizzled chunk offsets (elements)
    const int a_off1 = ((l4 + 4) ^ r7) * 8;
    const int arow = wm * (NI * 16) + l15;
    const int brow = wn * (NJ * 16) + l15;

    for (int t = 0; t < nK; ++t) {
        const bf16_t* __restrict__ Ab = Al[t & 1];
        const bf16_t* __restrict__ Bb = Bl[t & 1];
        bf16x8 bfv[NJ][2];
        bf16x8 af[NIH][2];
        // B frags for the whole tile (held in regs; read once)
        #pragma unroll
        for (int j = 0; j < NJ; ++j) {
            bfv[j][0] = *(const bf16x8*)&Bb[(brow + j * 16) * BK + a_off0];
            bfv[j][1] = *(const bf16x8*)&Bb[(brow + j * 16) * BK + a_off1];
        }
        #pragma unroll
        for (int ih = 0; ih < 2; ++ih) {
            #pragma unroll
            for (int i = 0; i < NIH; ++i) {
                af[i][0] = *(const bf16x8*)&Ab[(arow + (ih * NIH + i) * 16) * BK + a_off0];
                af[i][1] = *(const bf16x8*)&Ab[(arow + (ih * NIH + i) * 16) * BK + a_off1];
            }
            #pragma unroll
            for (int jh = 0; jh < 2; ++jh) {
                __builtin_amdgcn_s_setprio(1);
                #pragma unroll
                for (int kx = 0; kx < 2; ++kx)
                    #pragma unroll
                    for (int i = 0; i < NIH; ++i)
                        #pragma unroll
                        for (int j = 0; j < NJH; ++j)
                            acc[ih * NIH + i][jh * NJH + j] =
                                __builtin_amdgcn_mfma_f32_16x16x32_bf16(
                                    af[i][kx], bfv[jh * NJH + j][kx],
                                    acc[ih * NIH + i][jh * NJH + j], 0, 0, 0);
                __builtin_amdgcn_s_setprio(0);
            }
        }
        if (t + 1 < nK) {
            // all this wave's ds_reads of buf[t&1] complete (compiler's lgkm waits
            // before MFMA already guarantee it; explicit wait is belt & braces)
            asm volatile("s_waitcnt lgkmcnt(0)" ::: "memory");
            __builtin_amdgcn_sched_barrier(0);
            __builtin_amdgcn_s_barrier();      // every wave done READING buf[t&1]
            __builtin_amdgcn_sched_barrier(0);
            if (t + 2 < nK) {
                stage(t + 2, t & 1);           // write-after-read safe now
                // counted wait: retires tile t+1's loads, leaves tile t+2 in flight
                if constexpr (TOT == 8) asm volatile("s_waitcnt vmcnt(8)" ::: "memory");
                else                    asm volatile("s_waitcnt vmcnt(6)" ::: "memory");
            } else {
                asm volatile("s_waitcnt vmcnt(0)" ::: "memory");  // last prefetch drain
            }
            __builtin_amdgcn_sched_barrier(0);
            __builtin_amdgcn_s_barrier();      // tile t+1 visible to all waves
            __builtin_amdgcn_sched_barrier(0);
        }
    }

    if (MODE == 1) {
        const int isf32 = flag[0];
        float bz[NJ];
        #pragma unroll
        for (int j = 0; j < NJ; ++j)
            bz[j] = ldin(bias, b1_e + (size_t)(bn + wn * (NJ * 16) + j * 16 + l15), isf32);
        #pragma unroll
        for (int i = 0; i < NI; ++i) {
            #pragma unroll
            for (int r = 0; r < 4; ++r) {
                int m = bm + wm * (NI * 16) + i * 16 + l4 * 4 + r;
                float cf = coef[(size_t)m * 8];
                #pragma unroll
                for (int j = 0; j < NJ; ++j) {
                    float v = acc[i][j][r] + bz[j];
                    v = fmaxf(v, 0.f) * cf;
                    obf[(size_t)m * N + bn + wn * (NJ * 16) + j * 16 + l15] = (bf16_t)v;
                }
            }
        }
    } else {
        #pragma unroll
        for (int i = 0; i < NI; ++i) {
            #pragma unroll
            for (int r = 0; r < 4; ++r) {
                int m = bm + wm * (NI * 16) + i * 16 + l4 * 4 + r;
                float* orow = oacc + (size_t)m * N + bn + wn * (NJ * 16) + l15;
                #pragma unroll
                for (int j = 0; j < NJ; ++j)
                    orow[j * 16] += acc[i][j][r];
            }
        }
    }
}

// ---------------- launcher ----------------
extern "C" void kernel_launch(void* const* d_in, const int* in_sizes, int n_in,
                              void* d_out, int out_size, void* d_ws, size_t ws_size,
                              hipStream_t stream) {
    const void* x      = d_in[0];
    const void* gate_w = d_in[1];
    const void* gate_b = d_in[2];
    const void* sw1    = d_in[3];
    const void* sb1    = d_in[4];
    const void* sw2    = d_in[5];
    const void* sb2    = d_in[6];
    const void* rw1    = d_in[7];
    const void* rb1    = d_in[8];
    const void* rw2    = d_in[9];
    const void* rb2    = d_in[10];

    char* ws = (char*)d_ws;
    int* flag = (int*)ws;
    size_t off = 256;
    bf16_t* W1T = (bf16_t*)(ws + off); off += (size_t)Ff * Dd * sizeof(bf16_t);  // 8 MB
    bf16_t* W2T = (bf16_t*)(ws + off); off += (size_t)Oo * Ff * sizeof(bf16_t);  // 8 MB
    bf16_t* xb  = (bf16_t*)(ws + off); off += (size_t)Tn * Dd * sizeof(bf16_t);  // 16 MB
    float* coef = (float*)(ws + off);  off += (size_t)Tn * 8 * sizeof(float);    // 256 KB
    float* accb = (float*)(ws + off);  off += (size_t)Tn * Oo * sizeof(float);   // 32 MB
    bf16_t* Hs  = (bf16_t*)(ws + off);
    size_t rem = (ws_size > off) ? (ws_size - off) : 0;
    long tcap = (long)(rem / ((size_t)Ff * sizeof(bf16_t)));
    int Tc = (int)((tcap / 256) * 256);   // GEMM M-chunks must be multiples of 256
    if (Tc < 256) Tc = 256;
    if (Tc > Tn) Tc = Tn;

    detect_kernel<<<1, 256, 0, stream>>>((const unsigned int*)x, flag);
    cvt_x_kernel<<<(Tn * Dd) / 256, 256, 0, stream>>>(x, flag, xb);
    gate_kernel<<<Tn, 64, 0, stream>>>(x, gate_w, gate_b, flag, coef);
    init_acc_kernel<<<(Tn * Oo) / 256, 256, 0, stream>>>(coef, sb2, rb2, flag, accb);

    dim3 tb(32, 8);
    for (int j = 0; j < NEXP; ++j) {
        const void* w1 = (j < 2) ? sw1 : rw1;
        const void* w2 = (j < 2) ? sw2 : rw2;
        const void* b1 = (j < 2) ? sb1 : rb1;
        int je = (j < 2) ? j : (j - 2);
        size_t w1_e = (size_t)je * Dd * Ff;
        size_t w2_e = (size_t)je * Ff * Oo;
        size_t b1_e = (size_t)je * Ff;

        cvt_transpose_kernel<<<dim3(Ff / 32, Dd / 32), tb, 0, stream>>>(w1, w1_e, flag, W1T, Dd, Ff);
        cvt_transpose_kernel<<<dim3(Oo / 32, Ff / 32), tb, 0, stream>>>(w2, w2_e, flag, W2T, Ff, Oo);

        for (int tok0 = 0; tok0 < Tn; tok0 += Tc) {
            int tc = (Tn - tok0 < Tc) ? (Tn - tok0) : Tc;
            // GEMM1: [tc,1024] x [4096,1024]^T -> grid (tc/256, 16), 256x256 tile
            gemm_kernel<1, 256, 2><<<dim3(tc / 256, Ff / 256), 512, 0, stream>>>(
                xb + (size_t)tok0 * Dd, W1T, tc, Ff, Dd,
                b1, b1_e, flag, coef + (size_t)tok0 * 8 + j, Hs, nullptr);
            // GEMM2: [tc,4096] x [1024,4096]^T -> grid (tc/256, 8), 256x128 tile,
            // 4x2 wave grid (per-wave 64x64) so all 256 CUs get a block
            gemm_kernel<2, 128, 4><<<dim3(tc / 256, Oo / 128), 512, 0, stream>>>(
                Hs, W2T, tc, Oo, Ff, nullptr, 0, flag, nullptr, nullptr,
                accb + (size_t)tok0 * Oo);
        }
    }

    convert_kernel<<<(Tn * Oo) / 256, 256, 0, stream>>>(accb, flag, d_out);
}

// Round 2
// 1319.342 us; speedup vs baseline: 1.0625x; 1.0625x over previous
//
#include <hip/hip_runtime.h>

typedef __bf16 bf16_t;
typedef __bf16 bf16x8 __attribute__((ext_vector_type(8)));
typedef float f32x4 __attribute__((ext_vector_type(4)));

// Problem constants
constexpr int Tn = 4 * 2048;   // tokens = B*S
constexpr int Dd = 1024;
constexpr int Ff = 4096;
constexpr int Oo = 1024;
constexpr int NEXP = 6;        // 2 shared + 4 routed

// flag-conditional scalar input load (inputs may be f32 or bf16; detected at runtime)
__device__ __forceinline__ float ldin(const void* p, size_t i, int isf32) {
    return isf32 ? ((const float*)p)[i] : (float)((const bf16_t*)p)[i];
}

// ---------------- dtype detector ----------------
__global__ void detect_kernel(const unsigned int* __restrict__ xw, int* __restrict__ flag) {
    __shared__ int cnt;
    if (threadIdx.x == 0) cnt = 0;
    __syncthreads();
    int c = 0;
    for (int i = threadIdx.x; i < 16384; i += 256) {
        unsigned w = xw[i];
        if (((w >> 7) & 0xFFu) == 0xFFu) ++c;
    }
    atomicAdd(&cnt, c);
    __syncthreads();
    if (threadIdx.x == 0) flag[0] = (cnt >= 4) ? 1 : 0;
}

// ---------------- x -> bf16 ----------------
__global__ void cvt_x_kernel(const void* __restrict__ x, const int* __restrict__ flag,
                             bf16_t* __restrict__ xb) {
    int f = flag[0];
    size_t i = (size_t)blockIdx.x * 256 + threadIdx.x;
    xb[i] = (bf16_t)ldin(x, i, f);
}

// ---------------- convert+transpose: src(+eofs) [R][C] -> bf16 dst [C][R] ----------------
__global__ void cvt_transpose_kernel(const void* __restrict__ src, size_t eofs,
                                     const int* __restrict__ flag,
                                     bf16_t* __restrict__ dst, int R, int C) {
    __shared__ bf16_t tile[32][33];
    int f = flag[0];
    int c0 = blockIdx.x * 32, r0 = blockIdx.y * 32;
    int tx = threadIdx.x, ty = threadIdx.y;
    #pragma unroll
    for (int i = 0; i < 32; i += 8)
        tile[ty + i][tx] = (bf16_t)ldin(src, eofs + (size_t)(r0 + ty + i) * C + c0 + tx, f);
    __syncthreads();
    #pragma unroll
    for (int i = 0; i < 32; i += 8)
        dst[(size_t)(c0 + ty + i) * R + r0 + tx] = tile[tx][ty + i];
}

// ---------------- gating ----------------
__global__ void gate_kernel(const void* __restrict__ x, const void* __restrict__ gw,
                            const void* __restrict__ gb, const int* __restrict__ flag,
                            float* __restrict__ coef) {
    int f = flag[0];
    int t = blockIdx.x;
    int lane = threadIdx.x;  // 64 threads
    float a0 = 0.f, a1 = 0.f, a2 = 0.f, a3 = 0.f;
    for (int d = lane; d < Dd; d += 64) {
        float xv = ldin(x, (size_t)t * Dd + d, f);
        a0 += xv * ldin(gw, (size_t)d * 4 + 0, f);
        a1 += xv * ldin(gw, (size_t)d * 4 + 1, f);
        a2 += xv * ldin(gw, (size_t)d * 4 + 2, f);
        a3 += xv * ldin(gw, (size_t)d * 4 + 3, f);
    }
    #pragma unroll
    for (int off = 32; off; off >>= 1) {
        a0 += __shfl_xor(a0, off);
        a1 += __shfl_xor(a1, off);
        a2 += __shfl_xor(a2, off);
        a3 += __shfl_xor(a3, off);
    }
    if (lane == 0) {
        float l[4] = {a0 + ldin(gb, 0, f), a1 + ldin(gb, 1, f),
                      a2 + ldin(gb, 2, f), a3 + ldin(gb, 3, f)};
        float mx = fmaxf(fmaxf(l[0], l[1]), fmaxf(l[2], l[3]));
        float e[4], s = 0.f;
        #pragma unroll
        for (int i = 0; i < 4; ++i) { e[i] = expf(l[i] - mx); s += e[i]; }
        float w[4];
        #pragma unroll
        for (int i = 0; i < 4; ++i) w[i] = e[i] / s;
        int i0 = 0;
        for (int i = 1; i < 4; ++i) if (w[i] > w[i0]) i0 = i;   // ties -> lowest idx
        int i1 = -1;
        for (int i = 0; i < 4; ++i) { if (i == i0) continue; if (i1 < 0 || w[i] > w[i1]) i1 = i; }
        float c[8] = {0.5f, 0.5f, 0.f, 0.f, 0.f, 0.f, 0.f, 0.f};
        c[2 + i0] = w[i0];
        c[2 + i1] = w[i1];
        float* dst = coef + (size_t)t * 8;
        #pragma unroll
        for (int k = 0; k < 8; ++k) dst[k] = c[k];
    }
}

// ---------------- acc init: acc[t][o] = sum_j coef[t][j]*b2[j][o] ----------------
__global__ void init_acc_kernel(const float* __restrict__ coef, const void* __restrict__ sb2,
                                const void* __restrict__ rb2, const int* __restrict__ flag,
                                float* __restrict__ acc) {
    int f = flag[0];
    size_t idx = (size_t)blockIdx.x * 256 + threadIdx.x;
    int t = (int)(idx >> 10);          // O = 1024
    int o = (int)(idx & 1023);
    const float* c = coef + (size_t)t * 8;
    float v = c[0] * ldin(sb2, o, f) + c[1] * ldin(sb2, Oo + o, f)
            + c[2] * ldin(rb2, o, f) + c[3] * ldin(rb2, Oo + o, f)
            + c[4] * ldin(rb2, 2 * Oo + o, f) + c[5] * ldin(rb2, 3 * Oo + o, f);
    acc[idx] = v;
}

// ---------------- final convert ----------------
__global__ void convert_kernel(const float* __restrict__ acc, const int* __restrict__ flag,
                               void* __restrict__ out) {
    int f = flag[0];
    size_t idx = (size_t)blockIdx.x * 256 + threadIdx.x;
    float v = acc[idx];
    if (v != v) v = 333.0f;   // NaN sentinel for diagnosis
    if (f) ((float*)out)[idx] = v;
    else   ((bf16_t*)out)[idx] = (bf16_t)v;
}

// ---------------- GEMM core: C = A[M,K] * Bt[N,K]^T ----------------
// 256xBN_ tile, BK=64, 512 threads = 8 waves (WM_ x WN_ wave grid).
// 4-phase-per-K-tile pipelined schedule (m201-style T3+T4+T5):
//   phase = { ds_read subtile ; stage 1 half-panel ; s_barrier ; lgkmcnt(0) ;
//             setprio(1) ; MFMA quadrant ; setprio(0) ; s_barrier }
//   Quadrant order jh-major: (ih0,jh0) (ih1,jh0) (ih0,jh1) (ih1,jh1)
//     -> A-frags last read at phase 1, B-frags last read at phase 2.
//   Stage mapping (race-free by construction):
//     ph0: B-h0(t+1) -> Bl[b^1]  (other buffer: always safe)
//     ph1: B-h1(t+1) -> Bl[b^1]
//     ph2: A-h0(t+2) -> Al[b]    (A of tile t fully read at ph1 + barrier)
//     ph3: A-h1(t+2) -> Al[b]
//   Boundary: vmcnt(4) leaves exactly A(t+2)'s 4 loads in flight; everything
//   tile t+1 needs (A(t+1) staged during t-1, B(t+1) staged during t) is landed.
//   Never drains vmcnt to 0 in the main loop (T4).
// XOR bank-swizzle: LDS slot (row, c8) holds global chunk c8 ^ (row&7);
// read at chunk (k8f ^ (row&7)). glds dst stays linear (wave-uniform + lane*16).
// No XCD swizzle: natural mapping already clusters A-strip sharers per XCD
// (gridDim.x multiple of 8 -> XCD = blockIdx.x % 8).
// MODE 1: obf = bf16( relu(acc + bias[b1_e+n]) * coef[m*8] );  MODE 2: oacc += acc
template <int MODE, int BN_, int WM_>
__launch_bounds__(512, 2)
__global__ void gemm_kernel(const bf16_t* __restrict__ A, const bf16_t* __restrict__ Bt,
                            int M, int N, int K,
                            const void* __restrict__ bias, size_t b1_e,
                            const int* __restrict__ flag,
                            const float* __restrict__ coef,
                            bf16_t* __restrict__ obf, float* __restrict__ oacc) {
    constexpr int BM = 256, BK = 64;
    constexpr int WN_ = 8 / WM_;
    constexpr int NI = BM / (WM_ * 16);   // i-frags per wave
    constexpr int NJ = BN_ / (WN_ * 16);  // j-frags per wave
    constexpr int NIH = NI / 2;
    constexpr int NJH = NJ / 2;
    constexpr int LPH_B = BN_ / 128;      // glds per thread per B half-panel (1 or 2)
    constexpr int BHALF = BN_ * 4;        // LDS slots (8-elem chunks) per B half

    __shared__ __align__(16) bf16_t Al[2][BM * BK];
    __shared__ __align__(16) bf16_t Bl[2][BN_ * BK];

    const int tid = threadIdx.x;
    const int lane = tid & 63;
    const int wave = tid >> 6;
    const int wm = wave / WN_;
    const int wn = wave % WN_;
    const int l15 = lane & 15;
    const int l4 = lane >> 4;
    const int r7 = l15 & 7;

    const int bm = blockIdx.x * BM;
    const int bn = blockIdx.y * BN_;
    const int nK = K / BK;

    auto stageA = [&](int x, int h, int db) {
        const int k0 = x * BK;
        #pragma unroll
        for (int it = 0; it < 2; ++it) {
            int q = it * 512 + tid;
            int row = (q >> 3) + h * 128;
            int k8 = (q & 7) ^ ((q >> 3) & 7);
            const bf16_t* g = A + (size_t)(bm + row) * K + k0 + k8 * 8;
            __builtin_amdgcn_global_load_lds(
                (const __attribute__((address_space(1))) unsigned int*)g,
                (__attribute__((address_space(3))) unsigned int*)(&Al[db][(h * 1024 + q) * 8]),
                16, 0, 0);
        }
    };
    auto stageB = [&](int x, int h, int db) {
        const int k0 = x * BK;
        #pragma unroll
        for (int it = 0; it < LPH_B; ++it) {
            int q = it * 512 + tid;
            int row = (q >> 3) + h * (BN_ / 2);
            int k8 = (q & 7) ^ ((q >> 3) & 7);
            const bf16_t* g = Bt + (size_t)(bn + row) * K + k0 + k8 * 8;
            __builtin_amdgcn_global_load_lds(
                (const __attribute__((address_space(1))) unsigned int*)g,
                (__attribute__((address_space(3))) unsigned int*)(&Bl[db][(h * BHALF + q) * 8]),
                16, 0, 0);
        }
    };

    f32x4 acc[NI][NJ] = {};

    // prologue: A(0), B(0) -> buf0; A(1) -> buf1.  vmcnt(4) leaves A(1) flying.
    stageA(0, 0, 0); stageA(0, 1, 0);
    stageB(0, 0, 0); stageB(0, 1, 0);
    stageA(1, 0, 1); stageA(1, 1, 1);
    asm volatile("s_waitcnt vmcnt(4)" ::: "memory");
    __builtin_amdgcn_sched_barrier(0);
    __builtin_amdgcn_s_barrier();
    __builtin_amdgcn_sched_barrier(0);

    const int a_off0 = ((l4 + 0) ^ r7) * 8;   // swizzled chunk offsets (elements)
    const int a_off1 = ((l4 + 4) ^ r7) * 8;
    const int arow = wm * (NI * 16) + l15;
    const int brow = wn * (NJ * 16) + l15;

    for (int t = 0; t < nK; ++t) {
        const int b = t & 1;
        const bf16_t* __restrict__ Ab = Al[b];
        const bf16_t* __restrict__ Bb = Bl[b];
        const bool s1 = (t + 1 < nK);
        const bool s2 = (t + 2 < nK);

        bf16x8 af[NI][2];
        bf16x8 bv[NJH][2];

#define QUAD(IH, JH)                                                              \
    __builtin_amdgcn_s_setprio(1);                                                \
    _Pragma("unroll")                                                             \
    for (int kx = 0; kx < 2; ++kx)                                                \
        _Pragma("unroll")                                                         \
        for (int i = 0; i < NIH; ++i)                                             \
            _Pragma("unroll")                                                     \
            for (int j = 0; j < NJH; ++j)                                         \
                acc[(IH) * NIH + i][(JH) * NJH + j] =                             \
                    __builtin_amdgcn_mfma_f32_16x16x32_bf16(                      \
                        af[(IH) * NIH + i][kx], bv[j][kx],                        \
                        acc[(IH) * NIH + i][(JH) * NJH + j], 0, 0, 0);            \
    __builtin_amdgcn_s_setprio(0);

        // ---------------- phase 0: read af[ih0], bv[jh0]; stage B-h0(t+1) ----------------
        #pragma unroll
        for (int i = 0; i < NIH; ++i) {
            af[i][0] = *(const bf16x8*)&Ab[(arow + i * 16) * BK + a_off0];
            af[i][1] = *(const bf16x8*)&Ab[(arow + i * 16) * BK + a_off1];
        }
        #pragma unroll
        for (int j = 0; j < NJH; ++j) {
            bv[j][0] = *(const bf16x8*)&Bb[(brow + j * 16) * BK + a_off0];
            bv[j][1] = *(const bf16x8*)&Bb[(brow + j * 16) * BK + a_off1];
        }
        if (s1) stageB(t + 1, 0, b ^ 1);
        __builtin_amdgcn_s_barrier();
        asm volatile("s_waitcnt lgkmcnt(0)" ::: "memory");
        __builtin_amdgcn_sched_barrier(0);
        QUAD(0, 0)
        __builtin_amdgcn_s_barrier();

        // ---------------- phase 1: read af[ih1]; stage B-h1(t+1) ----------------
        #pragma unroll
        for (int i = 0; i < NIH; ++i) {
            af[NIH + i][0] = *(const bf16x8*)&Ab[(arow + (NIH + i) * 16) * BK + a_off0];
            af[NIH + i][1] = *(const bf16x8*)&Ab[(arow + (NIH + i) * 16) * BK + a_off1];
        }
        if (s1) stageB(t + 1, 1, b ^ 1);
        __builtin_amdgcn_s_barrier();
        asm volatile("s_waitcnt lgkmcnt(0)" ::: "memory");
        __builtin_amdgcn_sched_barrier(0);
        QUAD(1, 0)
        __builtin_amdgcn_s_barrier();

        // ---------------- phase 2: read bv[jh1] (overwrite); stage A-h0(t+2) ----------------
        #pragma unroll
        for (int j = 0; j < NJH; ++j) {
            bv[j][0] = *(const bf16x8*)&Bb[(brow + (NJH + j) * 16) * BK + a_off0];
            bv[j][1] = *(const bf16x8*)&Bb[(brow + (NJH + j) * 16) * BK + a_off1];
        }
        if (s2) stageA(t + 2, 0, b);
        __builtin_amdgcn_s_barrier();
        asm volatile("s_waitcnt lgkmcnt(0)" ::: "memory");
        __builtin_amdgcn_sched_barrier(0);
        QUAD(0, 1)
        __builtin_amdgcn_s_barrier();

        // ---------------- phase 3: no reads; stage A-h1(t+2) ----------------
        if (s2) stageA(t + 2, 1, b);
        __builtin_amdgcn_s_barrier();
        QUAD(1, 1)

        // ---------------- tile boundary ----------------
        if (s1) {
            __builtin_amdgcn_s_barrier();
            if (s2) { asm volatile("s_waitcnt vmcnt(4)" ::: "memory"); }
            else    { asm volatile("s_waitcnt vmcnt(0)" ::: "memory"); }
            __builtin_amdgcn_sched_barrier(0);
            __builtin_amdgcn_s_barrier();
        }
#undef QUAD
    }

    if (MODE == 1) {
        const int isf32 = flag[0];
        float bz[NJ];
        #pragma unroll
        for (int j = 0; j < NJ; ++j)
            bz[j] = ldin(bias, b1_e + (size_t)(bn + wn * (NJ * 16) + j * 16 + l15), isf32);
        #pragma unroll
        for (int i = 0; i < NI; ++i) {
            #pragma unroll
            for (int r = 0; r < 4; ++r) {
                int m = bm + wm * (NI * 16) + i * 16 + l4 * 4 + r;
                float cf = coef[(size_t)m * 8];
                #pragma unroll
                for (int j = 0; j < NJ; ++j) {
                    float v = acc[i][j][r] + bz[j];
                    v = fmaxf(v, 0.f) * cf;
                    obf[(size_t)m * N + bn + wn * (NJ * 16) + j * 16 + l15] = (bf16_t)v;
                }
            }
        }
    } else {
        #pragma unroll
        for (int i = 0; i < NI; ++i) {
            #pragma unroll
            for (int r = 0; r < 4; ++r) {
                int m = bm + wm * (NI * 16) + i * 16 + l4 * 4 + r;
                float* orow = oacc + (size_t)m * N + bn + wn * (NJ * 16) + l15;
                #pragma unroll
                for (int j = 0; j < NJ; ++j)
                    orow[j * 16] += acc[i][j][r];
            }
        }
    }
}

// ---------------- launcher ----------------
extern "C" void kernel_launch(void* const* d_in, const int* in_sizes, int n_in,
                              void* d_out, int out_size, void* d_ws, size_t ws_size,
                              hipStream_t stream) {
    const void* x      = d_in[0];
    const void* gate_w = d_in[1];
    const void* gate_b = d_in[2];
    const void* sw1    = d_in[3];
    const void* sb1    = d_in[4];
    const void* sw2    = d_in[5];
    const void* sb2    = d_in[6];
    const void* rw1    = d_in[7];
    const void* rb1    = d_in[8];
    const void* rw2    = d_in[9];
    const void* rb2    = d_in[10];

    char* ws = (char*)d_ws;
    int* flag = (int*)ws;
    size_t off = 256;
    bf16_t* W1T = (bf16_t*)(ws + off); off += (size_t)Ff * Dd * sizeof(bf16_t);  // 8 MB
    bf16_t* W2T = (bf16_t*)(ws + off); off += (size_t)Oo * Ff * sizeof(bf16_t);  // 8 MB
    bf16_t* xb  = (bf16_t*)(ws + off); off += (size_t)Tn * Dd * sizeof(bf16_t);  // 16 MB
    float* coef = (float*)(ws + off);  off += (size_t)Tn * 8 * sizeof(float);    // 256 KB
    float* accb = (float*)(ws + off);  off += (size_t)Tn * Oo * sizeof(float);   // 32 MB
    bf16_t* Hs  = (bf16_t*)(ws + off);
    size_t rem = (ws_size > off) ? (ws_size - off) : 0;
    long tcap = (long)(rem / ((size_t)Ff * sizeof(bf16_t)));
    int Tc = (int)((tcap / 256) * 256);   // GEMM M-chunks must be multiples of 256
    if (Tc < 256) Tc = 256;
    if (Tc > Tn) Tc = Tn;

    detect_kernel<<<1, 256, 0, stream>>>((const unsigned int*)x, flag);
    cvt_x_kernel<<<(Tn * Dd) / 256, 256, 0, stream>>>(x, flag, xb);
    gate_kernel<<<Tn, 64, 0, stream>>>(x, gate_w, gate_b, flag, coef);
    init_acc_kernel<<<(Tn * Oo) / 256, 256, 0, stream>>>(coef, sb2, rb2, flag, accb);

    dim3 tb(32, 8);
    for (int j = 0; j < NEXP; ++j) {
        const void* w1 = (j < 2) ? sw1 : rw1;
        const void* w2 = (j < 2) ? sw2 : rw2;
        const void* b1 = (j < 2) ? sb1 : rb1;
        int je = (j < 2) ? j : (j - 2);
        size_t w1_e = (size_t)je * Dd * Ff;
        size_t w2_e = (size_t)je * Ff * Oo;
        size_t b1_e = (size_t)je * Ff;

        cvt_transpose_kernel<<<dim3(Ff / 32, Dd / 32), tb, 0, stream>>>(w1, w1_e, flag, W1T, Dd, Ff);
        cvt_transpose_kernel<<<dim3(Oo / 32, Ff / 32), tb, 0, stream>>>(w2, w2_e, flag, W2T, Ff, Oo);

        for (int tok0 = 0; tok0 < Tn; tok0 += Tc) {
            int tc = (Tn - tok0 < Tc) ? (Tn - tok0) : Tc;
            // GEMM1: [tc,1024] x [4096,1024]^T -> grid (tc/256, 16), 256x256 tile,
            // waves 2M x 4N (per-wave 128x64 = best MFMA-per-ds_read ratio)
            gemm_kernel<1, 256, 2><<<dim3(tc / 256, Ff / 256), 512, 0, stream>>>(
                xb + (size_t)tok0 * Dd, W1T, tc, Ff, Dd,
                b1, b1_e, flag, coef + (size_t)tok0 * 8 + j, Hs, nullptr);
            // GEMM2: [tc,4096] x [1024,4096]^T -> grid (tc/256, 8), 256x128 tile,
            // waves 4M x 2N (per-wave 64x64), 256 blocks = 1 per CU
            gemm_kernel<2, 128, 4><<<dim3(tc / 256, Oo / 128), 512, 0, stream>>>(
                Hs, W2T, tc, Oo, Ff, nullptr, 0, flag, nullptr, nullptr,
                accb + (size_t)tok0 * Oo);
        }
    }

    convert_kernel<<<(Tn * Oo) / 256, 256, 0, stream>>>(accb, flag, d_out);
}

// Round 3
// 1302.752 us; speedup vs baseline: 1.0760x; 1.0127x over previous
//
#include <hip/hip_runtime.h>

typedef __bf16 bf16_t;
typedef __bf16 bf16x8 __attribute__((ext_vector_type(8)));
typedef float f32x4 __attribute__((ext_vector_type(4)));

// Problem constants
constexpr int Tn = 4 * 2048;   // tokens = B*S
constexpr int Dd = 1024;
constexpr int Ff = 4096;
constexpr int Oo = 1024;

// flag-conditional scalar input load (inputs may be f32 or bf16; detected at runtime)
__device__ __forceinline__ float ldin(const void* p, size_t i, int isf32) {
    return isf32 ? ((const float*)p)[i] : (float)((const bf16_t*)p)[i];
}

// ---------------- dtype detector ----------------
__global__ void detect_kernel(const unsigned int* __restrict__ xw, int* __restrict__ flag) {
    __shared__ int cnt;
    if (threadIdx.x == 0) cnt = 0;
    __syncthreads();
    int c = 0;
    for (int i = threadIdx.x; i < 16384; i += 256) {
        unsigned w = xw[i];
        if (((w >> 7) & 0xFFu) == 0xFFu) ++c;
    }
    atomicAdd(&cnt, c);
    __syncthreads();
    if (threadIdx.x == 0) flag[0] = (cnt >= 4) ? 1 : 0;
}

// ---------------- zero routing counters ----------------
__global__ void zero_cnt_kernel(int* __restrict__ cnt) {
    if (threadIdx.x < 4) cnt[threadIdx.x] = 0;
}

// ---------------- x -> bf16 ----------------
__global__ void cvt_x_kernel(const void* __restrict__ x, const int* __restrict__ flag,
                             bf16_t* __restrict__ xb) {
    int f = flag[0];
    size_t i = (size_t)blockIdx.x * 256 + threadIdx.x;
    xb[i] = (bf16_t)ldin(x, i, f);
}

// ---------------- convert+transpose: src(+eofs) [R][C] -> bf16 dst [C][R] ----------------
__global__ void cvt_transpose_kernel(const void* __restrict__ src, size_t eofs,
                                     const int* __restrict__ flag,
                                     bf16_t* __restrict__ dst, int R, int C) {
    __shared__ bf16_t tile[32][33];
    int f = flag[0];
    int c0 = blockIdx.x * 32, r0 = blockIdx.y * 32;
    int tx = threadIdx.x, ty = threadIdx.y;
    #pragma unroll
    for (int i = 0; i < 32; i += 8)
        tile[ty + i][tx] = (bf16_t)ldin(src, eofs + (size_t)(r0 + ty + i) * C + c0 + tx, f);
    __syncthreads();
    #pragma unroll
    for (int i = 0; i < 32; i += 8)
        dst[(size_t)(c0 + ty + i) * R + r0 + tx] = tile[tx][ty + i];
}

// ---------------- gating + token-list build ----------------
__global__ void gate_kernel(const void* __restrict__ x, const void* __restrict__ gw,
                            const void* __restrict__ gb, const int* __restrict__ flag,
                            float* __restrict__ coef, int* __restrict__ cnt,
                            int* __restrict__ tlist) {
    int f = flag[0];
    int t = blockIdx.x;
    int lane = threadIdx.x;  // 64 threads
    float a0 = 0.f, a1 = 0.f, a2 = 0.f, a3 = 0.f;
    for (int d = lane; d < Dd; d += 64) {
        float xv = ldin(x, (size_t)t * Dd + d, f);
        a0 += xv * ldin(gw, (size_t)d * 4 + 0, f);
        a1 += xv * ldin(gw, (size_t)d * 4 + 1, f);
        a2 += xv * ldin(gw, (size_t)d * 4 + 2, f);
        a3 += xv * ldin(gw, (size_t)d * 4 + 3, f);
    }
    #pragma unroll
    for (int off = 32; off; off >>= 1) {
        a0 += __shfl_xor(a0, off);
        a1 += __shfl_xor(a1, off);
        a2 += __shfl_xor(a2, off);
        a3 += __shfl_xor(a3, off);
    }
    if (lane == 0) {
        float l[4] = {a0 + ldin(gb, 0, f), a1 + ldin(gb, 1, f),
                      a2 + ldin(gb, 2, f), a3 + ldin(gb, 3, f)};
        float mx = fmaxf(fmaxf(l[0], l[1]), fmaxf(l[2], l[3]));
        float e[4], s = 0.f;
        #pragma unroll
        for (int i = 0; i < 4; ++i) { e[i] = expf(l[i] - mx); s += e[i]; }
        float w[4];
        #pragma unroll
        for (int i = 0; i < 4; ++i) w[i] = e[i] / s;
        int i0 = 0;
        for (int i = 1; i < 4; ++i) if (w[i] > w[i0]) i0 = i;   // ties -> lowest idx
        int i1 = -1;
        for (int i = 0; i < 4; ++i) { if (i == i0) continue; if (i1 < 0 || w[i] > w[i1]) i1 = i; }
        float c[8] = {0.5f, 0.5f, 0.f, 0.f, 0.f, 0.f, 0.f, 0.f};
        c[2 + i0] = w[i0];
        c[2 + i1] = w[i1];
        float* dst = coef + (size_t)t * 8;
        #pragma unroll
        for (int k = 0; k < 8; ++k) dst[k] = c[k];
        // append token to its two selected experts' lists (order irrelevant:
        // per-token results are independent of list position)
        int p0 = atomicAdd(&cnt[i0], 1);
        tlist[(size_t)i0 * Tn + p0] = t;
        int p1 = atomicAdd(&cnt[i1], 1);
        tlist[(size_t)i1 * Tn + p1] = t;
    }
}

// ---------------- routing finalize: pad counts to 128, sentinel-fill pads ----------------
__global__ void finalize_route_kernel(const int* __restrict__ cnt, int* __restrict__ cntp,
                                      int* __restrict__ tlist, float* __restrict__ coef) {
    int lane = threadIdx.x;  // 64 threads
    #pragma unroll
    for (int e = 0; e < 4; ++e) {
        int c = cnt[e]; if (c > Tn) c = Tn;
        int p = (c + 127) & ~127;
        if (lane == 0) cntp[e] = p;
        for (int i = c + lane; i < p; i += 64) tlist[(size_t)e * Tn + i] = Tn;  // sentinel
    }
    if (lane < 8) coef[(size_t)Tn * 8 + lane] = 0.f;  // sentinel token: zero coef
}

// ---------------- acc init: acc[t][o] = sum_j coef[t][j]*b2[j][o] ----------------
__global__ void init_acc_kernel(const float* __restrict__ coef, const void* __restrict__ sb2,
                                const void* __restrict__ rb2, const int* __restrict__ flag,
                                float* __restrict__ acc) {
    int f = flag[0];
    size_t idx = (size_t)blockIdx.x * 256 + threadIdx.x;
    int t = (int)(idx >> 10);          // O = 1024
    int o = (int)(idx & 1023);
    const float* c = coef + (size_t)t * 8;
    float v = c[0] * ldin(sb2, o, f) + c[1] * ldin(sb2, Oo + o, f)
            + c[2] * ldin(rb2, o, f) + c[3] * ldin(rb2, Oo + o, f)
            + c[4] * ldin(rb2, 2 * Oo + o, f) + c[5] * ldin(rb2, 3 * Oo + o, f);
    acc[idx] = v;
}

// ---------------- final convert ----------------
__global__ void convert_kernel(const float* __restrict__ acc, const int* __restrict__ flag,
                               void* __restrict__ out) {
    int f = flag[0];
    size_t idx = (size_t)blockIdx.x * 256 + threadIdx.x;
    float v = acc[idx];
    if (v != v) v = 333.0f;   // NaN sentinel for diagnosis
    if (f) ((float*)out)[idx] = v;
    else   ((bf16_t*)out)[idx] = (bf16_t)v;
}

// ---------------- GEMM core: C = A[M,K] * Bt[N,K]^T, 128x128 tile, BK=64 ----------------
// Proven round-0 structure (2 blocks/CU, implicit wave-level overlap — m114 mechanism).
// global_load_lds width-16 staging + XOR bank-swizzle:
//   LDS slot (row, c8s) holds global chunk k8 = c8s ^ (row&7)   (chunks of 8 bf16 = 16 B)
//   glds dst stays wave-uniform-base + lane*16 (required); only global src is permuted.
// MODE 1: dense G1: obf = bf16( relu(acc + bias[b1_e+n]) * coef[m*8] )
// MODE 2: dense G2: oacc += acc
// MODE 3: sparse G1 (routed): A rows gathered via tl[]; coef[token*8+joff]; early-exit
// MODE 4: sparse G2 (routed): output scatter-add to oacc[token]; early-exit
template <int MODE>
__launch_bounds__(256, 2)
__global__ void gemm_kernel(const bf16_t* __restrict__ A, const bf16_t* __restrict__ Bt,
                            int M, int N, int K,
                            const void* __restrict__ bias, size_t b1_e,
                            const int* __restrict__ flag,
                            const float* __restrict__ coef,
                            bf16_t* __restrict__ obf, float* __restrict__ oacc,
                            const int* __restrict__ tl, const int* __restrict__ cntp,
                            int tok0, int joff) {
    constexpr int BM = 128, BN = 128, BK = 64;

    if constexpr (MODE >= 3) {
        int rem = cntp[0] - tok0;               // remaining active rows in this chunk
        if ((int)blockIdx.x * BM >= rem) return; // uniform exit, before any barrier
    }

    __shared__ __align__(16) bf16_t Al[BM * BK];
    __shared__ __align__(16) bf16_t Bl[BN * BK];

    const int tid = threadIdx.x;
    const int lane = tid & 63;
    const int wave = tid >> 6;
    const int wm = wave & 1, wn = wave >> 1;   // 2x2 wave grid, each wave 64x64
    const int bm = blockIdx.x * BM;
    const int bn = blockIdx.y * BN;
    const int l15 = lane & 15;
    const int l4 = lane >> 4;
    const int r7 = l15 & 7;                    // row&7 for fragment rows (rows are l15 mod 16)

    // gathered A-row indices (4 fixed rows per thread across the whole K loop)
    int ar[4];
    if constexpr (MODE == 3) {
        #pragma unroll
        for (int it = 0; it < 4; ++it) ar[it] = tl[bm + (tid >> 3) + it * 32];
    }

    f32x4 acc[4][4] = {};

    for (int k0 = 0; k0 < K; k0 += BK) {
        #pragma unroll
        for (int it = 0; it < 4; ++it) {
            int q = it * 256 + tid;
            int row = q >> 3, c8s = q & 7;
            int k8 = c8s ^ (row & 7);
            const bf16_t* g;
            if constexpr (MODE == 3)
                g = A + (size_t)ar[it] * K + k0 + k8 * 8;
            else
                g = A + (size_t)(bm + row) * K + k0 + k8 * 8;
            __builtin_amdgcn_global_load_lds(
                (const __attribute__((address_space(1))) unsigned int*)g,
                (__attribute__((address_space(3))) unsigned int*)(&Al[q * 8]), 16, 0, 0);
        }
        #pragma unroll
        for (int it = 0; it < 4; ++it) {
            int q = it * 256 + tid;
            int row = q >> 3, c8s = q & 7;
            int k8 = c8s ^ (row & 7);
            const bf16_t* g = Bt + (size_t)(bn + row) * K + k0 + k8 * 8;
            __builtin_amdgcn_global_load_lds(
                (const __attribute__((address_space(1))) unsigned int*)g,
                (__attribute__((address_space(3))) unsigned int*)(&Bl[q * 8]), 16, 0, 0);
        }
        __syncthreads();   // emits s_waitcnt vmcnt(0) before s_barrier -> LDS valid
        #pragma unroll
        for (int kk = 0; kk < BK; kk += 32) {
            const int k8f = l4 + (kk >> 3);    // which 8-elem chunk this lane's fragment wants
            const int c8s = (k8f ^ r7) * 8;    // swizzled LDS chunk offset (elements)
            bf16x8 af[4], bfv[4];
            #pragma unroll
            for (int i = 0; i < 4; ++i)
                af[i] = *(const bf16x8*)&Al[(wm * 64 + i * 16 + l15) * BK + c8s];
            #pragma unroll
            for (int j = 0; j < 4; ++j)
                bfv[j] = *(const bf16x8*)&Bl[(wn * 64 + j * 16 + l15) * BK + c8s];
            #pragma unroll
            for (int i = 0; i < 4; ++i)
                #pragma unroll
                for (int j = 0; j < 4; ++j)
                    acc[i][j] = __builtin_amdgcn_mfma_f32_16x16x32_bf16(af[i], bfv[j], acc[i][j], 0, 0, 0);
        }
        __syncthreads();
    }

    if constexpr (MODE == 1 || MODE == 3) {
        int isf32 = flag[0];
        float bz[4];
        #pragma unroll
        for (int j = 0; j < 4; ++j)
            bz[j] = ldin(bias, b1_e + (size_t)(bn + wn * 64 + j * 16 + l15), isf32);
        #pragma unroll
        for (int i = 0; i < 4; ++i) {
            #pragma unroll
            for (int r = 0; r < 4; ++r) {
                int m = bm + wm * 64 + i * 16 + l4 * 4 + r;
                float cf;
                if constexpr (MODE == 3) {
                    int token = tl[m];
                    cf = coef[(size_t)token * 8 + joff];
                } else {
                    cf = coef[(size_t)m * 8];
                }
                #pragma unroll
                for (int j = 0; j < 4; ++j) {
                    float v = acc[i][j][r] + bz[j];
                    v = fmaxf(v, 0.f) * cf;
                    obf[(size_t)m * N + bn + wn * 64 + j * 16 + l15] = (bf16_t)v;
                }
            }
        }
    } else {
        #pragma unroll
        for (int i = 0; i < 4; ++i) {
            #pragma unroll
            for (int r = 0; r < 4; ++r) {
                int m = bm + wm * 64 + i * 16 + l4 * 4 + r;
                float* orow;
                if constexpr (MODE == 4) {
                    int token = tl[m];   // sentinel Tn -> dummy row (discarded)
                    orow = oacc + (size_t)token * N + bn + wn * 64 + l15;
                } else {
                    orow = oacc + (size_t)m * N + bn + wn * 64 + l15;
                }
                #pragma unroll
                for (int j = 0; j < 4; ++j)
                    orow[j * 16] += acc[i][j][r];
            }
        }
    }
}

// ---------------- launcher ----------------
extern "C" void kernel_launch(void* const* d_in, const int* in_sizes, int n_in,
                              void* d_out, int out_size, void* d_ws, size_t ws_size,
                              hipStream_t stream) {
    const void* x      = d_in[0];
    const void* gate_w = d_in[1];
    const void* gate_b = d_in[2];
    const void* sw1    = d_in[3];
    const void* sb1    = d_in[4];
    const void* sw2    = d_in[5];
    const void* sb2    = d_in[6];
    const void* rw1    = d_in[7];
    const void* rb1    = d_in[8];
    const void* rw2    = d_in[9];
    const void* rb2    = d_in[10];

    char* ws = (char*)d_ws;
    int* flag = (int*)ws;
    size_t off = 256;
    bf16_t* W1T = (bf16_t*)(ws + off); off += (size_t)Ff * Dd * sizeof(bf16_t);       // 8 MB
    bf16_t* W2T = (bf16_t*)(ws + off); off += (size_t)Oo * Ff * sizeof(bf16_t);       // 8 MB
    bf16_t* xb  = (bf16_t*)(ws + off); off += (size_t)Tn * Dd * sizeof(bf16_t);       // 16 MB
    float* coef = (float*)(ws + off);  off += (size_t)(Tn + 1) * 8 * sizeof(float);   // +sentinel
    off = (off + 255) & ~(size_t)255;
    int* cnt    = (int*)(ws + off);    off += 256;                                     // cnt[4]
    int* cntp   = (int*)(ws + off);    off += 256;                                     // cntp[4]
    int* tlist  = (int*)(ws + off);    off += (size_t)4 * Tn * sizeof(int);            // 128 KB
    off = (off + 255) & ~(size_t)255;
    float* accb = (float*)(ws + off);  off += (size_t)(Tn + 1) * Oo * sizeof(float);   // +dummy row
    off = (off + 255) & ~(size_t)255;
    bf16_t* Hs  = (bf16_t*)(ws + off);
    size_t rem = (ws_size > off) ? (ws_size - off) : 0;
    long tcap = (long)(rem / ((size_t)Ff * sizeof(bf16_t)));
    int Tc = (int)((tcap / 128) * 128);
    if (Tc < 128) Tc = 128;
    if (Tc > Tn) Tc = Tn;

    detect_kernel<<<1, 256, 0, stream>>>((const unsigned int*)x, flag);
    zero_cnt_kernel<<<1, 64, 0, stream>>>(cnt);
    cvt_x_kernel<<<(Tn * Dd) / 256, 256, 0, stream>>>(x, flag, xb);
    gate_kernel<<<Tn, 64, 0, stream>>>(x, gate_w, gate_b, flag, coef, cnt, tlist);
    finalize_route_kernel<<<1, 64, 0, stream>>>(cnt, cntp, tlist, coef);
    init_acc_kernel<<<(Tn * Oo) / 256, 256, 0, stream>>>(coef, sb2, rb2, flag, accb);

    dim3 tb(32, 8);

    // ---- shared experts: dense (coef = 0.5 each) ----
    for (int j = 0; j < 2; ++j) {
        size_t w1_e = (size_t)j * Dd * Ff;
        size_t w2_e = (size_t)j * Ff * Oo;
        size_t b1_e = (size_t)j * Ff;
        cvt_transpose_kernel<<<dim3(Ff / 32, Dd / 32), tb, 0, stream>>>(sw1, w1_e, flag, W1T, Dd, Ff);
        cvt_transpose_kernel<<<dim3(Oo / 32, Ff / 32), tb, 0, stream>>>(sw2, w2_e, flag, W2T, Ff, Oo);
        for (int tok0 = 0; tok0 < Tn; tok0 += Tc) {
            int tc = (Tn - tok0 < Tc) ? (Tn - tok0) : Tc;
            gemm_kernel<1><<<dim3(tc / 128, Ff / 128), 256, 0, stream>>>(
                xb + (size_t)tok0 * Dd, W1T, tc, Ff, Dd,
                sb1, b1_e, flag, coef + (size_t)tok0 * 8 + j, Hs, nullptr,
                nullptr, nullptr, 0, 0);
            gemm_kernel<2><<<dim3(tc / 128, Oo / 128), 256, 0, stream>>>(
                Hs, W2T, tc, Oo, Ff, nullptr, 0, flag, nullptr, nullptr,
                accb + (size_t)tok0 * Oo, nullptr, nullptr, 0, 0);
        }
    }

    // ---- routed experts: sparse over gathered token lists ----
    for (int e = 0; e < 4; ++e) {
        size_t w1_e = (size_t)e * Dd * Ff;
        size_t w2_e = (size_t)e * Ff * Oo;
        size_t b1_e = (size_t)e * Ff;
        cvt_transpose_kernel<<<dim3(Ff / 32, Dd / 32), tb, 0, stream>>>(rw1, w1_e, flag, W1T, Dd, Ff);
        cvt_transpose_kernel<<<dim3(Oo / 32, Ff / 32), tb, 0, stream>>>(rw2, w2_e, flag, W2T, Ff, Oo);
        for (int tok0 = 0; tok0 < Tn; tok0 += Tc) {
            int tc = (Tn - tok0 < Tc) ? (Tn - tok0) : Tc;
            // worst-case grid; blocks past cntp[e]-tok0 exit immediately
            gemm_kernel<3><<<dim3(tc / 128, Ff / 128), 256, 0, stream>>>(
                xb, W1T, tc, Ff, Dd,
                rb1, b1_e, flag, coef, Hs, nullptr,
                tlist + (size_t)e * Tn + tok0, cntp + e, tok0, 2 + e);
            gemm_kernel<4><<<dim3(tc / 128, Oo / 128), 256, 0, stream>>>(
                Hs, W2T, tc, Oo, Ff, nullptr, 0, flag, nullptr, nullptr,
                accb, tlist + (size_t)e * Tn + tok0, cntp + e, tok0, 0);
        }
    }

    convert_kernel<<<(Tn * Oo) / 256, 256, 0, stream>>>(accb, flag, d_out);
}

// Round 4
// 1202.124 us; speedup vs baseline: 1.1661x; 1.0837x over previous
//
#include <hip/hip_runtime.h>

typedef __bf16 bf16_t;
typedef __bf16 bf16x4 __attribute__((ext_vector_type(4)));
typedef __bf16 bf16x8 __attribute__((ext_vector_type(8)));
typedef float f32x4 __attribute__((ext_vector_type(4)));

// Problem constants
constexpr int Tn = 4 * 2048;   // tokens = B*S
constexpr int Dd = 1024;
constexpr int Ff = 4096;
constexpr int Oo = 1024;

// flag-conditional scalar input load (inputs may be f32 or bf16; detected at runtime)
__device__ __forceinline__ float ldin(const void* p, size_t i, int isf32) {
    return isf32 ? ((const float*)p)[i] : (float)((const bf16_t*)p)[i];
}

// ---------------- dtype detector ----------------
__global__ void detect_kernel(const unsigned int* __restrict__ xw, int* __restrict__ flag) {
    __shared__ int cnt;
    if (threadIdx.x == 0) cnt = 0;
    __syncthreads();
    int c = 0;
    for (int i = threadIdx.x; i < 16384; i += 256) {
        unsigned w = xw[i];
        if (((w >> 7) & 0xFFu) == 0xFFu) ++c;
    }
    atomicAdd(&cnt, c);
    __syncthreads();
    if (threadIdx.x == 0) flag[0] = (cnt >= 4) ? 1 : 0;
}

// ---------------- fused x->bf16 convert + gating (no atomics) ----------------
// One block (256 threads) per token. Each thread: 4 contiguous d-elems.
// Gate math in f32 from ORIGINAL x (identical to reference path + prior rounds).
__global__ void gate_fused_kernel(const void* __restrict__ x, const void* __restrict__ gw,
                                  const void* __restrict__ gb, const int* __restrict__ flag,
                                  bf16_t* __restrict__ xb, float* __restrict__ coef,
                                  int* __restrict__ sel) {
    const int f = flag[0];
    const int t = blockIdx.x;
    const int tid = threadIdx.x;       // 256
    const int lane = tid & 63, w = tid >> 6;
    const int d0 = tid * 4;

    float xv[4];
    bf16x4 xb4;
    if (f) {
        float4 v = *(const float4*)((const float*)x + (size_t)t * Dd + d0);
        xv[0] = v.x; xv[1] = v.y; xv[2] = v.z; xv[3] = v.w;
        #pragma unroll
        for (int i = 0; i < 4; ++i) xb4[i] = (bf16_t)xv[i];
    } else {
        xb4 = *(const bf16x4*)((const bf16_t*)x + (size_t)t * Dd + d0);
        #pragma unroll
        for (int i = 0; i < 4; ++i) xv[i] = (float)xb4[i];
    }
    *(bf16x4*)(xb + (size_t)t * Dd + d0) = xb4;

    float a[4] = {0.f, 0.f, 0.f, 0.f};
    #pragma unroll
    for (int i = 0; i < 4; ++i)
        #pragma unroll
        for (int e = 0; e < 4; ++e)
            a[e] += xv[i] * ldin(gw, (size_t)(d0 + i) * 4 + e, f);

    #pragma unroll
    for (int off = 32; off; off >>= 1)
        #pragma unroll
        for (int e = 0; e < 4; ++e) a[e] += __shfl_xor(a[e], off);

    __shared__ float red[4][4];
    if (lane == 0)
        #pragma unroll
        for (int e = 0; e < 4; ++e) red[w][e] = a[e];
    __syncthreads();

    if (tid == 0) {
        float l[4];
        #pragma unroll
        for (int e = 0; e < 4; ++e)
            l[e] = red[0][e] + red[1][e] + red[2][e] + red[3][e] + ldin(gb, e, f);
        float mx = fmaxf(fmaxf(l[0], l[1]), fmaxf(l[2], l[3]));
        float ex[4], s = 0.f;
        #pragma unroll
        for (int i = 0; i < 4; ++i) { ex[i] = expf(l[i] - mx); s += ex[i]; }
        float wgt[4];
        #pragma unroll
        for (int i = 0; i < 4; ++i) wgt[i] = ex[i] / s;
        int i0 = 0;
        for (int i = 1; i < 4; ++i) if (wgt[i] > wgt[i0]) i0 = i;   // ties -> lowest idx
        int i1 = -1;
        for (int i = 0; i < 4; ++i) { if (i == i0) continue; if (i1 < 0 || wgt[i] > wgt[i1]) i1 = i; }
        float c[8] = {0.5f, 0.5f, 0.f, 0.f, 0.f, 0.f, 0.f, 0.f};
        c[2 + i0] = wgt[i0];
        c[2 + i1] = wgt[i1];
        float* dst = coef + (size_t)t * 8;
        #pragma unroll
        for (int k = 0; k < 8; ++k) dst[k] = c[k];
        sel[t] = (1 << i0) | (1 << i1);
    }
}

// ---------------- token-list build: stable ballot compaction, one block per expert ----------------
__global__ void build_lists_kernel(const int* __restrict__ sel, int* __restrict__ cntp,
                                   int* __restrict__ tlist, float* __restrict__ coef) {
    const int e = blockIdx.x;          // 4 blocks
    const int tid = threadIdx.x;       // 256
    const int lane = tid & 63, w = tid >> 6;
    __shared__ int wsum[4];
    __shared__ int sbase;
    if (tid == 0) sbase = 0;
    __syncthreads();
    for (int t0 = 0; t0 < Tn; t0 += 256) {
        int t = t0 + tid;
        int p = (sel[t] >> e) & 1;
        unsigned long long b = __ballot(p);
        if (lane == 0) wsum[w] = __popcll(b);
        __syncthreads();
        int base = sbase;
        int woff = 0;
        for (int i = 0; i < w; ++i) woff += wsum[i];
        int rank = __popcll(b & ((1ull << lane) - 1ull));
        if (p) tlist[(size_t)e * Tn + base + woff + rank] = t;
        int tot = wsum[0] + wsum[1] + wsum[2] + wsum[3];
        __syncthreads();
        if (tid == 0) sbase = base + tot;
        __syncthreads();
    }
    int c = sbase;
    int cpad = (c + 127) & ~127;
    for (int i = c + tid; i < cpad; i += 256) tlist[(size_t)e * Tn + i] = Tn;  // sentinel
    if (tid == 0) cntp[e] = cpad;
    if (e == 0 && tid < 8) coef[(size_t)Tn * 8 + tid] = 0.f;  // sentinel token: zero coef
}

// ---------------- convert+transpose: src(+eofs) [R][C] -> bf16 dst [C][R] ----------------
__global__ void cvt_transpose_kernel(const void* __restrict__ src, size_t eofs,
                                     const int* __restrict__ flag,
                                     bf16_t* __restrict__ dst, int R, int C) {
    __shared__ bf16_t tile[32][33];
    int f = flag[0];
    int c0 = blockIdx.x * 32, r0 = blockIdx.y * 32;
    int tx = threadIdx.x, ty = threadIdx.y;
    #pragma unroll
    for (int i = 0; i < 32; i += 8)
        tile[ty + i][tx] = (bf16_t)ldin(src, eofs + (size_t)(r0 + ty + i) * C + c0 + tx, f);
    __syncthreads();
    #pragma unroll
    for (int i = 0; i < 32; i += 8)
        dst[(size_t)(c0 + ty + i) * R + r0 + tx] = tile[tx][ty + i];
}

// ---------------- acc init: acc[t][o] = sum_j coef[t][j]*b2[j][o] ----------------
__global__ void init_acc_kernel(const float* __restrict__ coef, const void* __restrict__ sb2,
                                const void* __restrict__ rb2, const int* __restrict__ flag,
                                float* __restrict__ acc) {
    int f = flag[0];
    size_t idx = (size_t)blockIdx.x * 256 + threadIdx.x;
    int t = (int)(idx >> 10);          // O = 1024
    int o = (int)(idx & 1023);
    const float* c = coef + (size_t)t * 8;
    float v = c[0] * ldin(sb2, o, f) + c[1] * ldin(sb2, Oo + o, f)
            + c[2] * ldin(rb2, o, f) + c[3] * ldin(rb2, Oo + o, f)
            + c[4] * ldin(rb2, 2 * Oo + o, f) + c[5] * ldin(rb2, 3 * Oo + o, f);
    acc[idx] = v;
}

// ---------------- final convert ----------------
__global__ void convert_kernel(const float* __restrict__ acc, const int* __restrict__ flag,
                               void* __restrict__ out) {
    int f = flag[0];
    size_t idx = (size_t)blockIdx.x * 256 + threadIdx.x;
    float v = acc[idx];
    if (v != v) v = 333.0f;   // NaN sentinel for diagnosis
    if (f) ((float*)out)[idx] = v;
    else   ((bf16_t*)out)[idx] = (bf16_t)v;
}

// ---------------- GEMM core: C = A[M,K] * Bt[N,K]^T, 128x128 tile, BK=64 ----------------
// Proven round-0 structure (2 blocks/CU, implicit wave-level overlap — m114 mechanism).
// global_load_lds width-16 staging + XOR bank-swizzle:
//   LDS slot (row, c8s) holds global chunk k8 = c8s ^ (row&7)   (chunks of 8 bf16 = 16 B)
//   glds dst stays wave-uniform-base + lane*16 (required); only global src is permuted.
// MODE 1: dense G1: obf = bf16( relu(acc + bias[b1_e+n]) * coef[m*8] )
// MODE 2: dense G2: oacc += acc
// MODE 3: sparse G1 (routed): A rows gathered via tl[]; coef[token*8+joff]; early-exit
// MODE 4: sparse G2 (routed): output scatter-add to oacc[token]; early-exit
template <int MODE>
__launch_bounds__(256, 2)
__global__ void gemm_kernel(const bf16_t* __restrict__ A, const bf16_t* __restrict__ Bt,
                            int M, int N, int K,
                            const void* __restrict__ bias, size_t b1_e,
                            const int* __restrict__ flag,
                            const float* __restrict__ coef,
                            bf16_t* __restrict__ obf, float* __restrict__ oacc,
                            const int* __restrict__ tl, const int* __restrict__ cntp,
                            int tok0, int joff) {
    constexpr int BM = 128, BN = 128, BK = 64;

    if constexpr (MODE >= 3) {
        int rem = cntp[0] - tok0;               // remaining active rows in this chunk
        if ((int)blockIdx.x * BM >= rem) return; // uniform exit, before any barrier
    }

    __shared__ __align__(16) bf16_t Al[BM * BK];
    __shared__ __align__(16) bf16_t Bl[BN * BK];

    const int tid = threadIdx.x;
    const int lane = tid & 63;
    const int wave = tid >> 6;
    const int wm = wave & 1, wn = wave >> 1;   // 2x2 wave grid, each wave 64x64
    const int bm = blockIdx.x * BM;
    const int bn = blockIdx.y * BN;
    const int l15 = lane & 15;
    const int l4 = lane >> 4;
    const int r7 = l15 & 7;                    // row&7 for fragment rows (rows are l15 mod 16)

    // gathered A-row indices (4 fixed rows per thread across the whole K loop)
    int ar[4];
    if constexpr (MODE == 3) {
        #pragma unroll
        for (int it = 0; it < 4; ++it) ar[it] = tl[bm + (tid >> 3) + it * 32];
    }

    f32x4 acc[4][4] = {};

    for (int k0 = 0; k0 < K; k0 += BK) {
        #pragma unroll
        for (int it = 0; it < 4; ++it) {
            int q = it * 256 + tid;
            int row = q >> 3, c8s = q & 7;
            int k8 = c8s ^ (row & 7);
            const bf16_t* g;
            if constexpr (MODE == 3)
                g = A + (size_t)ar[it] * K + k0 + k8 * 8;
            else
                g = A + (size_t)(bm + row) * K + k0 + k8 * 8;
            __builtin_amdgcn_global_load_lds(
                (const __attribute__((address_space(1))) unsigned int*)g,
                (__attribute__((address_space(3))) unsigned int*)(&Al[q * 8]), 16, 0, 0);
        }
        #pragma unroll
        for (int it = 0; it < 4; ++it) {
            int q = it * 256 + tid;
            int row = q >> 3, c8s = q & 7;
            int k8 = c8s ^ (row & 7);
            const bf16_t* g = Bt + (size_t)(bn + row) * K + k0 + k8 * 8;
            __builtin_amdgcn_global_load_lds(
                (const __attribute__((address_space(1))) unsigned int*)g,
                (__attribute__((address_space(3))) unsigned int*)(&Bl[q * 8]), 16, 0, 0);
        }
        __syncthreads();   // emits s_waitcnt vmcnt(0) before s_barrier -> LDS valid
        #pragma unroll
        for (int kk = 0; kk < BK; kk += 32) {
            const int k8f = l4 + (kk >> 3);    // which 8-elem chunk this lane's fragment wants
            const int c8s = (k8f ^ r7) * 8;    // swizzled LDS chunk offset (elements)
            bf16x8 af[4], bfv[4];
            #pragma unroll
            for (int i = 0; i < 4; ++i)
                af[i] = *(const bf16x8*)&Al[(wm * 64 + i * 16 + l15) * BK + c8s];
            #pragma unroll
            for (int j = 0; j < 4; ++j)
                bfv[j] = *(const bf16x8*)&Bl[(wn * 64 + j * 16 + l15) * BK + c8s];
            #pragma unroll
            for (int i = 0; i < 4; ++i)
                #pragma unroll
                for (int j = 0; j < 4; ++j)
                    acc[i][j] = __builtin_amdgcn_mfma_f32_16x16x32_bf16(af[i], bfv[j], acc[i][j], 0, 0, 0);
        }
        __syncthreads();
    }

    if constexpr (MODE == 1 || MODE == 3) {
        int isf32 = flag[0];
        float bz[4];
        #pragma unroll
        for (int j = 0; j < 4; ++j)
            bz[j] = ldin(bias, b1_e + (size_t)(bn + wn * 64 + j * 16 + l15), isf32);
        #pragma unroll
        for (int i = 0; i < 4; ++i) {
            #pragma unroll
            for (int r = 0; r < 4; ++r) {
                int m = bm + wm * 64 + i * 16 + l4 * 4 + r;
                float cf;
                if constexpr (MODE == 3) {
                    int token = tl[m];
                    cf = coef[(size_t)token * 8 + joff];
                } else {
                    cf = coef[(size_t)m * 8];
                }
                #pragma unroll
                for (int j = 0; j < 4; ++j) {
                    float v = acc[i][j][r] + bz[j];
                    v = fmaxf(v, 0.f) * cf;
                    obf[(size_t)m * N + bn + wn * 64 + j * 16 + l15] = (bf16_t)v;
                }
            }
        }
    } else {
        #pragma unroll
        for (int i = 0; i < 4; ++i) {
            #pragma unroll
            for (int r = 0; r < 4; ++r) {
                int m = bm + wm * 64 + i * 16 + l4 * 4 + r;
                float* orow;
                if constexpr (MODE == 4) {
                    int token = tl[m];   // sentinel Tn -> dummy row (discarded)
                    orow = oacc + (size_t)token * N + bn + wn * 64 + l15;
                } else {
                    orow = oacc + (size_t)m * N + bn + wn * 64 + l15;
                }
                #pragma unroll
                for (int j = 0; j < 4; ++j)
                    orow[j * 16] += acc[i][j][r];
            }
        }
    }
}

// ---------------- launcher ----------------
extern "C" void kernel_launch(void* const* d_in, const int* in_sizes, int n_in,
                              void* d_out, int out_size, void* d_ws, size_t ws_size,
                              hipStream_t stream) {
    const void* x      = d_in[0];
    const void* gate_w = d_in[1];
    const void* gate_b = d_in[2];
    const void* sw1    = d_in[3];
    const void* sb1    = d_in[4];
    const void* sw2    = d_in[5];
    const void* sb2    = d_in[6];
    const void* rw1    = d_in[7];
    const void* rb1    = d_in[8];
    const void* rw2    = d_in[9];
    const void* rb2    = d_in[10];

    char* ws = (char*)d_ws;
    int* flag = (int*)ws;
    size_t off = 256;
    bf16_t* W1T = (bf16_t*)(ws + off); off += (size_t)Ff * Dd * sizeof(bf16_t);       // 8 MB
    bf16_t* W2T = (bf16_t*)(ws + off); off += (size_t)Oo * Ff * sizeof(bf16_t);       // 8 MB
    bf16_t* xb  = (bf16_t*)(ws + off); off += (size_t)Tn * Dd * sizeof(bf16_t);       // 16 MB
    float* coef = (float*)(ws + off);  off += (size_t)(Tn + 1) * 8 * sizeof(float);   // +sentinel
    off = (off + 255) & ~(size_t)255;
    int* sel    = (int*)(ws + off);    off += (size_t)Tn * sizeof(int);                // 32 KB
    off = (off + 255) & ~(size_t)255;
    int* cntp   = (int*)(ws + off);    off += 256;                                     // cntp[4]
    int* tlist  = (int*)(ws + off);    off += (size_t)4 * Tn * sizeof(int);            // 128 KB
    off = (off + 255) & ~(size_t)255;
    float* accb = (float*)(ws + off);  off += (size_t)(Tn + 1) * Oo * sizeof(float);   // +dummy row
    off = (off + 255) & ~(size_t)255;
    bf16_t* Hs  = (bf16_t*)(ws + off);
    size_t rem = (ws_size > off) ? (ws_size - off) : 0;
    long tcap = (long)(rem / ((size_t)Ff * sizeof(bf16_t)));
    int Tc = (int)((tcap / 128) * 128);
    if (Tc < 128) Tc = 128;
    if (Tc > Tn) Tc = Tn;

    detect_kernel<<<1, 256, 0, stream>>>((const unsigned int*)x, flag);
    gate_fused_kernel<<<Tn, 256, 0, stream>>>(x, gate_w, gate_b, flag, xb, coef, sel);
    build_lists_kernel<<<4, 256, 0, stream>>>(sel, cntp, tlist, coef);
    init_acc_kernel<<<(Tn * Oo) / 256, 256, 0, stream>>>(coef, sb2, rb2, flag, accb);

    dim3 tb(32, 8);

    // ---- shared experts: dense (coef = 0.5 each) ----
    for (int j = 0; j < 2; ++j) {
        size_t w1_e = (size_t)j * Dd * Ff;
        size_t w2_e = (size_t)j * Ff * Oo;
        size_t b1_e = (size_t)j * Ff;
        cvt_transpose_kernel<<<dim3(Ff / 32, Dd / 32), tb, 0, stream>>>(sw1, w1_e, flag, W1T, Dd, Ff);
        cvt_transpose_kernel<<<dim3(Oo / 32, Ff / 32), tb, 0, stream>>>(sw2, w2_e, flag, W2T, Ff, Oo);
        for (int tok0 = 0; tok0 < Tn; tok0 += Tc) {
            int tc = (Tn - tok0 < Tc) ? (Tn - tok0) : Tc;
            gemm_kernel<1><<<dim3(tc / 128, Ff / 128), 256, 0, stream>>>(
                xb + (size_t)tok0 * Dd, W1T, tc, Ff, Dd,
                sb1, b1_e, flag, coef + (size_t)tok0 * 8 + j, Hs, nullptr,
                nullptr, nullptr, 0, 0);
            gemm_kernel<2><<<dim3(tc / 128, Oo / 128), 256, 0, stream>>>(
                Hs, W2T, tc, Oo, Ff, nullptr, 0, flag, nullptr, nullptr,
                accb + (size_t)tok0 * Oo, nullptr, nullptr, 0, 0);
        }
    }

    // ---- routed experts: sparse over gathered token lists ----
    for (int e = 0; e < 4; ++e) {
        size_t w1_e = (size_t)e * Dd * Ff;
        size_t w2_e = (size_t)e * Ff * Oo;
        size_t b1_e = (size_t)e * Ff;
        cvt_transpose_kernel<<<dim3(Ff / 32, Dd / 32), tb, 0, stream>>>(rw1, w1_e, flag, W1T, Dd, Ff);
        cvt_transpose_kernel<<<dim3(Oo / 32, Ff / 32), tb, 0, stream>>>(rw2, w2_e, flag, W2T, Ff, Oo);
        for (int tok0 = 0; tok0 < Tn; tok0 += Tc) {
            int tc = (Tn - tok0 < Tc) ? (Tn - tok0) : Tc;
            // worst-case grid; blocks past cntp[e]-tok0 exit immediately
            gemm_kernel<3><<<dim3(tc / 128, Ff / 128), 256, 0, stream>>>(
                xb, W1T, tc, Ff, Dd,
                rb1, b1_e, flag, coef, Hs, nullptr,
                tlist + (size_t)e * Tn + tok0, cntp + e, tok0, 2 + e);
            gemm_kernel<4><<<dim3(tc / 128, Oo / 128), 256, 0, stream>>>(
                Hs, W2T, tc, Oo, Ff, nullptr, 0, flag, nullptr, nullptr,
                accb, tlist + (size_t)e * Tn + tok0, cntp + e, tok0, 0);
        }
    }

    convert_kernel<<<(Tn * Oo) / 256, 256, 0, stream>>>(accb, flag, d_out);
}

// Round 5
// 1186.965 us; speedup vs baseline: 1.1810x; 1.0128x over previous
//
#include <hip/hip_runtime.h>

typedef __bf16 bf16_t;
typedef __bf16 bf16x4 __attribute__((ext_vector_type(4)));
typedef __bf16 bf16x8 __attribute__((ext_vector_type(8)));
typedef float f32x4 __attribute__((ext_vector_type(4)));

// Problem constants
constexpr int Tn = 4 * 2048;   // tokens = B*S
constexpr int Dd = 1024;
constexpr int Ff = 4096;
constexpr int Oo = 1024;

// flag-conditional scalar input load (inputs may be f32 or bf16; detected at runtime)
__device__ __forceinline__ float ldin(const void* p, size_t i, int isf32) {
    return isf32 ? ((const float*)p)[i] : (float)((const bf16_t*)p)[i];
}

// ---------------- dtype detector ----------------
__global__ void detect_kernel(const unsigned int* __restrict__ xw, int* __restrict__ flag) {
    __shared__ int cnt;
    if (threadIdx.x == 0) cnt = 0;
    __syncthreads();
    int c = 0;
    for (int i = threadIdx.x; i < 16384; i += 256) {
        unsigned w = xw[i];
        if (((w >> 7) & 0xFFu) == 0xFFu) ++c;
    }
    atomicAdd(&cnt, c);
    __syncthreads();
    if (threadIdx.x == 0) flag[0] = (cnt >= 4) ? 1 : 0;
}

// ---------------- fused x->bf16 convert + gating (no atomics) ----------------
__global__ void gate_fused_kernel(const void* __restrict__ x, const void* __restrict__ gw,
                                  const void* __restrict__ gb, const int* __restrict__ flag,
                                  bf16_t* __restrict__ xb, float* __restrict__ coef,
                                  int* __restrict__ sel) {
    const int f = flag[0];
    const int t = blockIdx.x;
    const int tid = threadIdx.x;       // 256
    const int lane = tid & 63, w = tid >> 6;
    const int d0 = tid * 4;

    float xv[4];
    bf16x4 xb4;
    if (f) {
        float4 v = *(const float4*)((const float*)x + (size_t)t * Dd + d0);
        xv[0] = v.x; xv[1] = v.y; xv[2] = v.z; xv[3] = v.w;
        #pragma unroll
        for (int i = 0; i < 4; ++i) xb4[i] = (bf16_t)xv[i];
    } else {
        xb4 = *(const bf16x4*)((const bf16_t*)x + (size_t)t * Dd + d0);
        #pragma unroll
        for (int i = 0; i < 4; ++i) xv[i] = (float)xb4[i];
    }
    *(bf16x4*)(xb + (size_t)t * Dd + d0) = xb4;

    float a[4] = {0.f, 0.f, 0.f, 0.f};
    #pragma unroll
    for (int i = 0; i < 4; ++i)
        #pragma unroll
        for (int e = 0; e < 4; ++e)
            a[e] += xv[i] * ldin(gw, (size_t)(d0 + i) * 4 + e, f);

    #pragma unroll
    for (int off = 32; off; off >>= 1)
        #pragma unroll
        for (int e = 0; e < 4; ++e) a[e] += __shfl_xor(a[e], off);

    __shared__ float red[4][4];
    if (lane == 0)
        #pragma unroll
        for (int e = 0; e < 4; ++e) red[w][e] = a[e];
    __syncthreads();

    if (tid == 0) {
        float l[4];
        #pragma unroll
        for (int e = 0; e < 4; ++e)
            l[e] = red[0][e] + red[1][e] + red[2][e] + red[3][e] + ldin(gb, e, f);
        float mx = fmaxf(fmaxf(l[0], l[1]), fmaxf(l[2], l[3]));
        float ex[4], s = 0.f;
        #pragma unroll
        for (int i = 0; i < 4; ++i) { ex[i] = expf(l[i] - mx); s += ex[i]; }
        float wgt[4];
        #pragma unroll
        for (int i = 0; i < 4; ++i) wgt[i] = ex[i] / s;
        int i0 = 0;
        for (int i = 1; i < 4; ++i) if (wgt[i] > wgt[i0]) i0 = i;   // ties -> lowest idx
        int i1 = -1;
        for (int i = 0; i < 4; ++i) { if (i == i0) continue; if (i1 < 0 || wgt[i] > wgt[i1]) i1 = i; }
        float c[8] = {0.5f, 0.5f, 0.f, 0.f, 0.f, 0.f, 0.f, 0.f};
        c[2 + i0] = wgt[i0];
        c[2 + i1] = wgt[i1];
        float* dst = coef + (size_t)t * 8;
        #pragma unroll
        for (int k = 0; k < 8; ++k) dst[k] = c[k];
        sel[t] = (1 << i0) | (1 << i1);
    }
}

// ---------------- token-list build: stable ballot compaction, one block per expert ----------------
__global__ void build_lists_kernel(const int* __restrict__ sel, int* __restrict__ cntp,
                                   int* __restrict__ tlist, float* __restrict__ coef) {
    const int e = blockIdx.x;          // 4 blocks
    const int tid = threadIdx.x;       // 256
    const int lane = tid & 63, w = tid >> 6;
    __shared__ int wsum[4];
    __shared__ int sbase;
    if (tid == 0) sbase = 0;
    __syncthreads();
    for (int t0 = 0; t0 < Tn; t0 += 256) {
        int t = t0 + tid;
        int p = (sel[t] >> e) & 1;
        unsigned long long b = __ballot(p);
        if (lane == 0) wsum[w] = __popcll(b);
        __syncthreads();
        int base = sbase;
        int woff = 0;
        for (int i = 0; i < w; ++i) woff += wsum[i];
        int rank = __popcll(b & ((1ull << lane) - 1ull));
        if (p) tlist[(size_t)e * Tn + base + woff + rank] = t;
        int tot = wsum[0] + wsum[1] + wsum[2] + wsum[3];
        __syncthreads();
        if (tid == 0) sbase = base + tot;
        __syncthreads();
    }
    int c = sbase;
    int cpad = (c + 127) & ~127;
    for (int i = c + tid; i < cpad; i += 256) tlist[(size_t)e * Tn + i] = Tn;  // sentinel
    if (tid == 0) cntp[e] = cpad;
    if (e == 0 && tid < 8) coef[(size_t)Tn * 8 + tid] = 0.f;  // sentinel token: zero coef
}

// ---------------- vectorized convert+transpose: src(+eofs) [R][C] -> bf16 dst [C][R] ----------------
// 64x64 tile, 256 threads. f32 path: float4 loads (16B/lane); store: bf16x8 (16B/lane).
__global__ void transpose_kernel(const void* __restrict__ src, size_t eofs,
                                 const int* __restrict__ flag,
                                 bf16_t* __restrict__ dst, int R, int C) {
    __shared__ bf16_t tile[64][68];    // 68 pad: 8B-aligned rows for bf16x4 writes
    const int f = flag[0];
    const int c0 = blockIdx.x * 64, r0 = blockIdx.y * 64;
    const int tid = threadIdx.x;       // 256
    if (f) {
        #pragma unroll
        for (int it = 0; it < 4; ++it) {
            int idx = it * 256 + tid;          // 1024 float4 chunks
            int r = idx >> 4, c4 = (idx & 15) * 4;
            float4 v = *(const float4*)((const float*)src + eofs + (size_t)(r0 + r) * C + c0 + c4);
            bf16x4 b4;
            b4[0] = (bf16_t)v.x; b4[1] = (bf16_t)v.y; b4[2] = (bf16_t)v.z; b4[3] = (bf16_t)v.w;
            *(bf16x4*)&tile[r][c4] = b4;
        }
    } else {
        #pragma unroll
        for (int it = 0; it < 2; ++it) {
            int idx = it * 256 + tid;          // 512 chunks of 8 bf16
            int r = idx >> 3, c8 = (idx & 7) * 8;
            bf16x8 v = *(const bf16x8*)((const bf16_t*)src + eofs + (size_t)(r0 + r) * C + c0 + c8);
            #pragma unroll
            for (int j = 0; j < 4; ++j) ((bf16x4*)&tile[r][c8])[0][j] = v[j];
            #pragma unroll
            for (int j = 0; j < 4; ++j) ((bf16x4*)&tile[r][c8 + 4])[0][j] = v[4 + j];
        }
    }
    __syncthreads();
    #pragma unroll
    for (int it = 0; it < 2; ++it) {
        int idx = it * 256 + tid;              // 512 = 64 cols x 8 row-chunks
        int col = idx >> 3, rc = (idx & 7) * 8;
        bf16x8 v;
        #pragma unroll
        for (int j = 0; j < 8; ++j) v[j] = tile[rc + j][col];
        *(bf16x8*)(dst + (size_t)(c0 + col) * R + r0 + rc) = v;
    }
}

// ---------------- acc init: acc[t][o] = sum_j coef[t][j]*b2[j][o] ----------------
__global__ void init_acc_kernel(const float* __restrict__ coef, const void* __restrict__ sb2,
                                const void* __restrict__ rb2, const int* __restrict__ flag,
                                float* __restrict__ acc) {
    int f = flag[0];
    size_t idx = (size_t)blockIdx.x * 256 + threadIdx.x;
    int t = (int)(idx >> 10);          // O = 1024
    int o = (int)(idx & 1023);
    const float* c = coef + (size_t)t * 8;
    float v = c[0] * ldin(sb2, o, f) + c[1] * ldin(sb2, Oo + o, f)
            + c[2] * ldin(rb2, o, f) + c[3] * ldin(rb2, Oo + o, f)
            + c[4] * ldin(rb2, 2 * Oo + o, f) + c[5] * ldin(rb2, 3 * Oo + o, f);
    acc[idx] = v;
}

// ---------------- final convert ----------------
__global__ void convert_kernel(const float* __restrict__ acc, const int* __restrict__ flag,
                               void* __restrict__ out) {
    int f = flag[0];
    size_t idx = (size_t)blockIdx.x * 256 + threadIdx.x;
    float v = acc[idx];
    if (v != v) v = 333.0f;   // NaN sentinel for diagnosis
    if (f) ((float*)out)[idx] = v;
    else   ((bf16_t*)out)[idx] = (bf16_t)v;
}

// ---------------- GEMM core: C = A[M,K] * Bt[N,K]^T, 128xBN tile, BK=64 ----------------
// Proven round-0 structure (>=2 blocks/CU, implicit wave-level overlap — m114 mechanism).
// global_load_lds width-16 staging + XOR bank-swizzle.
// MODE 1: dense G1: obf = bf16( relu(acc + bias[b1_e+n]) * coef[m*8] )
// MODE 2: dense G2: oacc += acc
// MODE 3: sparse G1 (routed): A rows gathered via tl[]; coef[token*8+joff]; early-exit
// MODE 4: sparse G2 (routed): output scatter-add to oacc[token]; early-exit
//         BN=64 for MODE 4: active grid 32x16 = 512 blocks (2+/CU) instead of 1/CU.
template <int MODE, int BN>
__device__ __forceinline__ void gemm_body(const bf16_t* __restrict__ A, const bf16_t* __restrict__ Bt,
                                          int M, int N, int K,
                                          const void* __restrict__ bias, size_t b1_e,
                                          const int* __restrict__ flag,
                                          const float* __restrict__ coef,
                                          bf16_t* __restrict__ obf, float* __restrict__ oacc,
                                          const int* __restrict__ tl, const int* __restrict__ cntp,
                                          int tok0, int joff) {
    constexpr int BM = 128, BK = 64;
    constexpr int NJ = BN / 32;               // j-frags per wave (wave covers BN/2 cols)
    constexpr int BLOADS = BN / 32;           // B-staging glds per thread

    if constexpr (MODE >= 3) {
        int rem = cntp[0] - tok0;               // remaining active rows in this chunk
        if ((int)blockIdx.x * BM >= rem) return; // uniform exit, before any barrier
    }

    __shared__ __align__(16) bf16_t Al[BM * BK];
    __shared__ __align__(16) bf16_t Bl[BN * BK];

    const int tid = threadIdx.x;
    const int lane = tid & 63;
    const int wave = tid >> 6;
    const int wm = wave & 1, wn = wave >> 1;   // 2x2 wave grid: 64 rows x BN/2 cols each
    const int bm = blockIdx.x * BM;
    const int bn = blockIdx.y * BN;
    const int l15 = lane & 15;
    const int l4 = lane >> 4;
    const int r7 = l15 & 7;

    // gathered A-row indices (4 fixed rows per thread across the whole K loop)
    int ar[4];
    if constexpr (MODE == 3) {
        #pragma unroll
        for (int it = 0; it < 4; ++it) ar[it] = tl[bm + (tid >> 3) + it * 32];
    }

    f32x4 acc[4][NJ] = {};

    for (int k0 = 0; k0 < K; k0 += BK) {
        #pragma unroll
        for (int it = 0; it < 4; ++it) {
            int q = it * 256 + tid;
            int row = q >> 3, c8s = q & 7;
            int k8 = c8s ^ (row & 7);
            const bf16_t* g;
            if constexpr (MODE == 3)
                g = A + (size_t)ar[it] * K + k0 + k8 * 8;
            else
                g = A + (size_t)(bm + row) * K + k0 + k8 * 8;
            __builtin_amdgcn_global_load_lds(
                (const __attribute__((address_space(1))) unsigned int*)g,
                (__attribute__((address_space(3))) unsigned int*)(&Al[q * 8]), 16, 0, 0);
        }
        #pragma unroll
        for (int it = 0; it < BLOADS; ++it) {
            int q = it * 256 + tid;
            int row = q >> 3, c8s = q & 7;
            int k8 = c8s ^ (row & 7);
            const bf16_t* g = Bt + (size_t)(bn + row) * K + k0 + k8 * 8;
            __builtin_amdgcn_global_load_lds(
                (const __attribute__((address_space(1))) unsigned int*)g,
                (__attribute__((address_space(3))) unsigned int*)(&Bl[q * 8]), 16, 0, 0);
        }
        __syncthreads();   // emits s_waitcnt vmcnt(0) before s_barrier -> LDS valid
        #pragma unroll
        for (int kk = 0; kk < BK; kk += 32) {
            const int k8f = l4 + (kk >> 3);
            const int c8s = (k8f ^ r7) * 8;
            bf16x8 af[4], bfv[NJ];
            #pragma unroll
            for (int i = 0; i < 4; ++i)
                af[i] = *(const bf16x8*)&Al[(wm * 64 + i * 16 + l15) * BK + c8s];
            #pragma unroll
            for (int j = 0; j < NJ; ++j)
                bfv[j] = *(const bf16x8*)&Bl[(wn * (BN / 2) + j * 16 + l15) * BK + c8s];
            #pragma unroll
            for (int i = 0; i < 4; ++i)
                #pragma unroll
                for (int j = 0; j < NJ; ++j)
                    acc[i][j] = __builtin_amdgcn_mfma_f32_16x16x32_bf16(af[i], bfv[j], acc[i][j], 0, 0, 0);
        }
        __syncthreads();
    }

    if constexpr (MODE == 1 || MODE == 3) {
        int isf32 = flag[0];
        float bz[NJ];
        #pragma unroll
        for (int j = 0; j < NJ; ++j)
            bz[j] = ldin(bias, b1_e + (size_t)(bn + wn * (BN / 2) + j * 16 + l15), isf32);
        #pragma unroll
        for (int i = 0; i < 4; ++i) {
            #pragma unroll
            for (int r = 0; r < 4; ++r) {
                int m = bm + wm * 64 + i * 16 + l4 * 4 + r;
                float cf;
                if constexpr (MODE == 3) {
                    int token = tl[m];
                    cf = coef[(size_t)token * 8 + joff];
                } else {
                    cf = coef[(size_t)m * 8];
                }
                #pragma unroll
                for (int j = 0; j < NJ; ++j) {
                    float v = acc[i][j][r] + bz[j];
                    v = fmaxf(v, 0.f) * cf;
                    obf[(size_t)m * N + bn + wn * (BN / 2) + j * 16 + l15] = (bf16_t)v;
                }
            }
        }
    } else {
        #pragma unroll
        for (int i = 0; i < 4; ++i) {
            #pragma unroll
            for (int r = 0; r < 4; ++r) {
                int m = bm + wm * 64 + i * 16 + l4 * 4 + r;
                float* orow;
                if constexpr (MODE == 4) {
                    int token = tl[m];   // sentinel Tn -> dummy row (discarded)
                    orow = oacc + (size_t)token * N + bn + wn * (BN / 2) + l15;
                } else {
                    orow = oacc + (size_t)m * N + bn + wn * (BN / 2) + l15;
                }
                #pragma unroll
                for (int j = 0; j < NJ; ++j)
                    orow[j * 16] += acc[i][j][r];
            }
        }
    }
}

// Named wrappers (distinct rocprof kernel names per phase)
__launch_bounds__(256, 2)
__global__ void gemm_sh1_kernel(const bf16_t* __restrict__ A, const bf16_t* __restrict__ Bt,
                                int M, int N, int K, const void* __restrict__ bias, size_t b1_e,
                                const int* __restrict__ flag, const float* __restrict__ coef,
                                bf16_t* __restrict__ obf) {
    gemm_body<1, 128>(A, Bt, M, N, K, bias, b1_e, flag, coef, obf, nullptr, nullptr, nullptr, 0, 0);
}
__launch_bounds__(256, 2)
__global__ void gemm_sh2_kernel(const bf16_t* __restrict__ A, const bf16_t* __restrict__ Bt,
                                int M, int N, int K, float* __restrict__ oacc) {
    gemm_body<2, 128>(A, Bt, M, N, K, nullptr, 0, nullptr, nullptr, nullptr, oacc, nullptr, nullptr, 0, 0);
}
__launch_bounds__(256, 2)
__global__ void gemm_rt1_kernel(const bf16_t* __restrict__ A, const bf16_t* __restrict__ Bt,
                                int M, int N, int K, const void* __restrict__ bias, size_t b1_e,
                                const int* __restrict__ flag, const float* __restrict__ coef,
                                bf16_t* __restrict__ obf, const int* __restrict__ tl,
                                const int* __restrict__ cntp, int tok0, int joff) {
    gemm_body<3, 128>(A, Bt, M, N, K, bias, b1_e, flag, coef, obf, nullptr, tl, cntp, tok0, joff);
}
__launch_bounds__(256, 2)
__global__ void gemm_rt2_kernel(const bf16_t* __restrict__ A, const bf16_t* __restrict__ Bt,
                                int M, int N, int K, float* __restrict__ oacc,
                                const int* __restrict__ tl, const int* __restrict__ cntp, int tok0) {
    gemm_body<4, 64>(A, Bt, M, N, K, nullptr, 0, nullptr, nullptr, nullptr, oacc, tl, cntp, tok0, 0);
}

// ---------------- launcher ----------------
extern "C" void kernel_launch(void* const* d_in, const int* in_sizes, int n_in,
                              void* d_out, int out_size, void* d_ws, size_t ws_size,
                              hipStream_t stream) {
    const void* x      = d_in[0];
    const void* gate_w = d_in[1];
    const void* gate_b = d_in[2];
    const void* sw1    = d_in[3];
    const void* sb1    = d_in[4];
    const void* sw2    = d_in[5];
    const void* sb2    = d_in[6];
    const void* rw1    = d_in[7];
    const void* rb1    = d_in[8];
    const void* rw2    = d_in[9];
    const void* rb2    = d_in[10];

    char* ws = (char*)d_ws;
    int* flag = (int*)ws;
    size_t off = 256;
    bf16_t* W1T = (bf16_t*)(ws + off); off += (size_t)Ff * Dd * sizeof(bf16_t);       // 8 MB
    bf16_t* W2T = (bf16_t*)(ws + off); off += (size_t)Oo * Ff * sizeof(bf16_t);       // 8 MB
    bf16_t* xb  = (bf16_t*)(ws + off); off += (size_t)Tn * Dd * sizeof(bf16_t);       // 16 MB
    float* coef = (float*)(ws + off);  off += (size_t)(Tn + 1) * 8 * sizeof(float);   // +sentinel
    off = (off + 255) & ~(size_t)255;
    int* sel    = (int*)(ws + off);    off += (size_t)Tn * sizeof(int);                // 32 KB
    off = (off + 255) & ~(size_t)255;
    int* cntp   = (int*)(ws + off);    off += 256;                                     // cntp[4]
    int* tlist  = (int*)(ws + off);    off += (size_t)4 * Tn * sizeof(int);            // 128 KB
    off = (off + 255) & ~(size_t)255;
    float* accb = (float*)(ws + off);  off += (size_t)(Tn + 1) * Oo * sizeof(float);   // +dummy row
    off = (off + 255) & ~(size_t)255;
    bf16_t* Hs  = (bf16_t*)(ws + off);
    size_t rem = (ws_size > off) ? (ws_size - off) : 0;
    long tcap = (long)(rem / ((size_t)Ff * sizeof(bf16_t)));
    int Tc = (int)((tcap / 128) * 128);
    if (Tc < 128) Tc = 128;
    if (Tc > Tn) Tc = Tn;

    detect_kernel<<<1, 256, 0, stream>>>((const unsigned int*)x, flag);
    gate_fused_kernel<<<Tn, 256, 0, stream>>>(x, gate_w, gate_b, flag, xb, coef, sel);
    build_lists_kernel<<<4, 256, 0, stream>>>(sel, cntp, tlist, coef);
    init_acc_kernel<<<(Tn * Oo) / 256, 256, 0, stream>>>(coef, sb2, rb2, flag, accb);

    // ---- shared experts: dense (coef = 0.5 each) ----
    for (int j = 0; j < 2; ++j) {
        size_t w1_e = (size_t)j * Dd * Ff;
        size_t w2_e = (size_t)j * Ff * Oo;
        size_t b1_e = (size_t)j * Ff;
        transpose_kernel<<<dim3(Ff / 64, Dd / 64), 256, 0, stream>>>(sw1, w1_e, flag, W1T, Dd, Ff);
        transpose_kernel<<<dim3(Oo / 64, Ff / 64), 256, 0, stream>>>(sw2, w2_e, flag, W2T, Ff, Oo);
        for (int tok0 = 0; tok0 < Tn; tok0 += Tc) {
            int tc = (Tn - tok0 < Tc) ? (Tn - tok0) : Tc;
            gemm_sh1_kernel<<<dim3(tc / 128, Ff / 128), 256, 0, stream>>>(
                xb + (size_t)tok0 * Dd, W1T, tc, Ff, Dd,
                sb1, b1_e, flag, coef + (size_t)tok0 * 8 + j, Hs);
            gemm_sh2_kernel<<<dim3(tc / 128, Oo / 128), 256, 0, stream>>>(
                Hs, W2T, tc, Oo, Ff, accb + (size_t)tok0 * Oo);
        }
    }

    // ---- routed experts: sparse over gathered token lists ----
    for (int e = 0; e < 4; ++e) {
        size_t w1_e = (size_t)e * Dd * Ff;
        size_t w2_e = (size_t)e * Ff * Oo;
        size_t b1_e = (size_t)e * Ff;
        transpose_kernel<<<dim3(Ff / 64, Dd / 64), 256, 0, stream>>>(rw1, w1_e, flag, W1T, Dd, Ff);
        transpose_kernel<<<dim3(Oo / 64, Ff / 64), 256, 0, stream>>>(rw2, w2_e, flag, W2T, Ff, Oo);
        for (int tok0 = 0; tok0 < Tn; tok0 += Tc) {
            int tc = (Tn - tok0 < Tc) ? (Tn - tok0) : Tc;
            // worst-case grids; blocks past cntp[e]-tok0 exit immediately
            gemm_rt1_kernel<<<dim3(tc / 128, Ff / 128), 256, 0, stream>>>(
                xb, W1T, tc, Ff, Dd,
                rb1, b1_e, flag, coef, Hs,
                tlist + (size_t)e * Tn + tok0, cntp + e, tok0, 2 + e);
            gemm_rt2_kernel<<<dim3(tc / 128, Oo / 64), 256, 0, stream>>>(
                Hs, W2T, tc, Oo, Ff, accb,
                tlist + (size_t)e * Tn + tok0, cntp + e, tok0);
        }
    }

    convert_kernel<<<(Tn * Oo) / 256, 256, 0, stream>>>(accb, flag, d_out);
}

// Round 6
// 1166.118 us; speedup vs baseline: 1.2021x; 1.0179x over previous
//
#include <hip/hip_runtime.h>

typedef __bf16 bf16_t;
typedef __bf16 bf16x4 __attribute__((ext_vector_type(4)));
typedef __bf16 bf16x8 __attribute__((ext_vector_type(8)));
typedef float f32x4 __attribute__((ext_vector_type(4)));

// Problem constants
constexpr int Tn = 4 * 2048;   // tokens = B*S
constexpr int Dd = 1024;
constexpr int Ff = 4096;
constexpr int Oo = 1024;

// flag-conditional scalar input load (inputs may be f32 or bf16; detected at runtime)
__device__ __forceinline__ float ldin(const void* p, size_t i, int isf32) {
    return isf32 ? ((const float*)p)[i] : (float)((const bf16_t*)p)[i];
}

// ---------------- dtype detector ----------------
__global__ void detect_kernel(const unsigned int* __restrict__ xw, int* __restrict__ flag) {
    __shared__ int cnt;
    if (threadIdx.x == 0) cnt = 0;
    __syncthreads();
    int c = 0;
    for (int i = threadIdx.x; i < 16384; i += 256) {
        unsigned w = xw[i];
        if (((w >> 7) & 0xFFu) == 0xFFu) ++c;
    }
    atomicAdd(&cnt, c);
    __syncthreads();
    if (threadIdx.x == 0) flag[0] = (cnt >= 4) ? 1 : 0;
}

// ---------------- fused x->bf16 convert + gating (no atomics) ----------------
__global__ void gate_fused_kernel(const void* __restrict__ x, const void* __restrict__ gw,
                                  const void* __restrict__ gb, const int* __restrict__ flag,
                                  bf16_t* __restrict__ xb, float* __restrict__ coef,
                                  int* __restrict__ sel) {
    const int f = flag[0];
    const int t = blockIdx.x;
    const int tid = threadIdx.x;       // 256
    const int lane = tid & 63, w = tid >> 6;
    const int d0 = tid * 4;

    float xv[4];
    bf16x4 xb4;
    if (f) {
        float4 v = *(const float4*)((const float*)x + (size_t)t * Dd + d0);
        xv[0] = v.x; xv[1] = v.y; xv[2] = v.z; xv[3] = v.w;
        #pragma unroll
        for (int i = 0; i < 4; ++i) xb4[i] = (bf16_t)xv[i];
    } else {
        xb4 = *(const bf16x4*)((const bf16_t*)x + (size_t)t * Dd + d0);
        #pragma unroll
        for (int i = 0; i < 4; ++i) xv[i] = (float)xb4[i];
    }
    *(bf16x4*)(xb + (size_t)t * Dd + d0) = xb4;

    float a[4] = {0.f, 0.f, 0.f, 0.f};
    #pragma unroll
    for (int i = 0; i < 4; ++i)
        #pragma unroll
        for (int e = 0; e < 4; ++e)
            a[e] += xv[i] * ldin(gw, (size_t)(d0 + i) * 4 + e, f);

    #pragma unroll
    for (int off = 32; off; off >>= 1)
        #pragma unroll
        for (int e = 0; e < 4; ++e) a[e] += __shfl_xor(a[e], off);

    __shared__ float red[4][4];
    if (lane == 0)
        #pragma unroll
        for (int e = 0; e < 4; ++e) red[w][e] = a[e];
    __syncthreads();

    if (tid == 0) {
        float l[4];
        #pragma unroll
        for (int e = 0; e < 4; ++e)
            l[e] = red[0][e] + red[1][e] + red[2][e] + red[3][e] + ldin(gb, e, f);
        float mx = fmaxf(fmaxf(l[0], l[1]), fmaxf(l[2], l[3]));
        float ex[4], s = 0.f;
        #pragma unroll
        for (int i = 0; i < 4; ++i) { ex[i] = expf(l[i] - mx); s += ex[i]; }
        float wgt[4];
        #pragma unroll
        for (int i = 0; i < 4; ++i) wgt[i] = ex[i] / s;
        int i0 = 0;
        for (int i = 1; i < 4; ++i) if (wgt[i] > wgt[i0]) i0 = i;   // ties -> lowest idx
        int i1 = -1;
        for (int i = 0; i < 4; ++i) { if (i == i0) continue; if (i1 < 0 || wgt[i] > wgt[i1]) i1 = i; }
        float c[8] = {0.5f, 0.5f, 0.f, 0.f, 0.f, 0.f, 0.f, 0.f};
        c[2 + i0] = wgt[i0];
        c[2 + i1] = wgt[i1];
        float* dst = coef + (size_t)t * 8;
        #pragma unroll
        for (int k = 0; k < 8; ++k) dst[k] = c[k];
        sel[t] = (1 << i0) | (1 << i1);
    }
}

// ---------------- token-list build: stable ballot compaction, one block per expert ----------------
__global__ void build_lists_kernel(const int* __restrict__ sel, int* __restrict__ cntp,
                                   int* __restrict__ tlist, float* __restrict__ coef) {
    const int e = blockIdx.x;          // 4 blocks
    const int tid = threadIdx.x;       // 256
    const int lane = tid & 63, w = tid >> 6;
    __shared__ int wsum[4];
    __shared__ int sbase;
    if (tid == 0) sbase = 0;
    __syncthreads();
    for (int t0 = 0; t0 < Tn; t0 += 256) {
        int t = t0 + tid;
        int p = (sel[t] >> e) & 1;
        unsigned long long b = __ballot(p);
        if (lane == 0) wsum[w] = __popcll(b);
        __syncthreads();
        int base = sbase;
        int woff = 0;
        for (int i = 0; i < w; ++i) woff += wsum[i];
        int rank = __popcll(b & ((1ull << lane) - 1ull));
        if (p) tlist[(size_t)e * Tn + base + woff + rank] = t;
        int tot = wsum[0] + wsum[1] + wsum[2] + wsum[3];
        __syncthreads();
        if (tid == 0) sbase = base + tot;
        __syncthreads();
    }
    int c = sbase;
    int cpad = (c + 127) & ~127;
    for (int i = c + tid; i < cpad; i += 256) tlist[(size_t)e * Tn + i] = Tn;  // sentinel
    if (tid == 0) cntp[e] = cpad;
    if (e == 0 && tid < 8) coef[(size_t)Tn * 8 + tid] = 0.f;  // sentinel token: zero coef
}

// ---------------- token compaction: xg[m] = xb[tl[m]] (sentinel -> row 0; coef=0 kills it) ----------------
__global__ void gather_kernel(const bf16_t* __restrict__ xb, const int* __restrict__ tl,
                              const int* __restrict__ cntp, bf16_t* __restrict__ xg) {
    int m = blockIdx.x * 2 + (threadIdx.x >> 7);   // 2 rows per 256-thread block
    if (m >= cntp[0]) return;
    int t = tl[m];
    const bf16_t* src = (t < Tn) ? (xb + (size_t)t * Dd) : xb;
    int c = (threadIdx.x & 127) * 8;
    *(bf16x8*)(xg + (size_t)m * Dd + c) = *(const bf16x8*)(src + c);
}

// ---------------- vectorized convert+transpose: src(+eofs) [R][C] -> bf16 dst [C][R] ----------------
__global__ void transpose_kernel(const void* __restrict__ src, size_t eofs,
                                 const int* __restrict__ flag,
                                 bf16_t* __restrict__ dst, int R, int C) {
    __shared__ bf16_t tile[64][68];    // 68 pad: 8B-aligned rows for bf16x4 writes
    const int f = flag[0];
    const int c0 = blockIdx.x * 64, r0 = blockIdx.y * 64;
    const int tid = threadIdx.x;       // 256
    if (f) {
        #pragma unroll
        for (int it = 0; it < 4; ++it) {
            int idx = it * 256 + tid;          // 1024 float4 chunks
            int r = idx >> 4, c4 = (idx & 15) * 4;
            float4 v = *(const float4*)((const float*)src + eofs + (size_t)(r0 + r) * C + c0 + c4);
            bf16x4 b4;
            b4[0] = (bf16_t)v.x; b4[1] = (bf16_t)v.y; b4[2] = (bf16_t)v.z; b4[3] = (bf16_t)v.w;
            *(bf16x4*)&tile[r][c4] = b4;
        }
    } else {
        #pragma unroll
        for (int it = 0; it < 2; ++it) {
            int idx = it * 256 + tid;          // 512 chunks of 8 bf16
            int r = idx >> 3, c8 = (idx & 7) * 8;
            bf16x8 v = *(const bf16x8*)((const bf16_t*)src + eofs + (size_t)(r0 + r) * C + c0 + c8);
            #pragma unroll
            for (int j = 0; j < 4; ++j) ((bf16x4*)&tile[r][c8])[0][j] = v[j];
            #pragma unroll
            for (int j = 0; j < 4; ++j) ((bf16x4*)&tile[r][c8 + 4])[0][j] = v[4 + j];
        }
    }
    __syncthreads();
    #pragma unroll
    for (int it = 0; it < 2; ++it) {
        int idx = it * 256 + tid;              // 512 = 64 cols x 8 row-chunks
        int col = idx >> 3, rc = (idx & 7) * 8;
        bf16x8 v;
        #pragma unroll
        for (int j = 0; j < 8; ++j) v[j] = tile[rc + j][col];
        *(bf16x8*)(dst + (size_t)(c0 + col) * R + r0 + rc) = v;
    }
}

// ---------------- acc init: acc[t][o] = sum_j coef[t][j]*b2[j][o] ----------------
__global__ void init_acc_kernel(const float* __restrict__ coef, const void* __restrict__ sb2,
                                const void* __restrict__ rb2, const int* __restrict__ flag,
                                float* __restrict__ acc) {
    int f = flag[0];
    size_t idx = (size_t)blockIdx.x * 256 + threadIdx.x;
    int t = (int)(idx >> 10);          // O = 1024
    int o = (int)(idx & 1023);
    const float* c = coef + (size_t)t * 8;
    float v = c[0] * ldin(sb2, o, f) + c[1] * ldin(sb2, Oo + o, f)
            + c[2] * ldin(rb2, o, f) + c[3] * ldin(rb2, Oo + o, f)
            + c[4] * ldin(rb2, 2 * Oo + o, f) + c[5] * ldin(rb2, 3 * Oo + o, f);
    acc[idx] = v;
}

// ---------------- final convert ----------------
__global__ void convert_kernel(const float* __restrict__ acc, const int* __restrict__ flag,
                               void* __restrict__ out) {
    int f = flag[0];
    size_t idx = (size_t)blockIdx.x * 256 + threadIdx.x;
    float v = acc[idx];
    if (v != v) v = 333.0f;   // NaN sentinel for diagnosis
    if (f) ((float*)out)[idx] = v;
    else   ((bf16_t*)out)[idx] = (bf16_t)v;
}

// ---------------- GEMM core: C = A[M,K] * Bt[N,K]^T, BMxBN tile, BK=64 ----------------
// Proven round-0 structure (m114 implicit wave-level overlap).
// global_load_lds width-16 staging + XOR bank-swizzle.
// MODE 1: dense G1: obf = bf16( relu(acc + bias[b1_e+n]) * coef[m*8] )
// MODE 2: dense G2: oacc += acc
// MODE 3: routed G1: A = compacted xg (dense reads); coef gathered via tl[]; early-exit
// MODE 4: routed G2: output scatter-add to oacc[token]; early-exit.
//         BM=64 -> active grid 64x8 = 512 blocks (2/CU) to dodge the 1-block/CU cliff.
template <int MODE, int BM, int BN>
__device__ __forceinline__ void gemm_body(const bf16_t* __restrict__ A, const bf16_t* __restrict__ Bt,
                                          int M, int N, int K,
                                          const void* __restrict__ bias, size_t b1_e,
                                          const int* __restrict__ flag,
                                          const float* __restrict__ coef,
                                          bf16_t* __restrict__ obf, float* __restrict__ oacc,
                                          const int* __restrict__ tl, const int* __restrict__ cntp,
                                          int tok0, int joff) {
    constexpr int BK = 64;
    constexpr int NI = BM / 32;               // i-frags per wave (wave covers BM/2 rows)
    constexpr int NJ = BN / 32;               // j-frags per wave (wave covers BN/2 cols)
    constexpr int ALOADS = BM / 32;           // A-staging glds per thread
    constexpr int BLOADS = BN / 32;           // B-staging glds per thread

    if constexpr (MODE >= 3) {
        int rem = cntp[0] - tok0;               // remaining active rows in this chunk
        if ((int)blockIdx.x * BM >= rem) return; // uniform exit, before any barrier
    }

    __shared__ __align__(16) bf16_t Al[BM * BK];
    __shared__ __align__(16) bf16_t Bl[BN * BK];

    const int tid = threadIdx.x;
    const int lane = tid & 63;
    const int wave = tid >> 6;
    const int wm = wave & 1, wn = wave >> 1;   // 2x2 wave grid: BM/2 rows x BN/2 cols each
    const int bm = blockIdx.x * BM;
    const int bn = blockIdx.y * BN;
    const int l15 = lane & 15;
    const int l4 = lane >> 4;
    const int r7 = l15 & 7;

    f32x4 acc[NI][NJ] = {};

    for (int k0 = 0; k0 < K; k0 += BK) {
        #pragma unroll
        for (int it = 0; it < ALOADS; ++it) {
            int q = it * 256 + tid;
            int row = q >> 3, c8s = q & 7;
            int k8 = c8s ^ (row & 7);
            const bf16_t* g = A + (size_t)(bm + row) * K + k0 + k8 * 8;
            __builtin_amdgcn_global_load_lds(
                (const __attribute__((address_space(1))) unsigned int*)g,
                (__attribute__((address_space(3))) unsigned int*)(&Al[q * 8]), 16, 0, 0);
        }
        #pragma unroll
        for (int it = 0; it < BLOADS; ++it) {
            int q = it * 256 + tid;
            int row = q >> 3, c8s = q & 7;
            int k8 = c8s ^ (row & 7);
            const bf16_t* g = Bt + (size_t)(bn + row) * K + k0 + k8 * 8;
            __builtin_amdgcn_global_load_lds(
                (const __attribute__((address_space(1))) unsigned int*)g,
                (__attribute__((address_space(3))) unsigned int*)(&Bl[q * 8]), 16, 0, 0);
        }
        __syncthreads();   // emits s_waitcnt vmcnt(0) before s_barrier -> LDS valid
        #pragma unroll
        for (int kk = 0; kk < BK; kk += 32) {
            const int k8f = l4 + (kk >> 3);
            const int c8s = (k8f ^ r7) * 8;
            bf16x8 af[NI], bfv[NJ];
            #pragma unroll
            for (int i = 0; i < NI; ++i)
                af[i] = *(const bf16x8*)&Al[(wm * (NI * 16) + i * 16 + l15) * BK + c8s];
            #pragma unroll
            for (int j = 0; j < NJ; ++j)
                bfv[j] = *(const bf16x8*)&Bl[(wn * (NJ * 16) + j * 16 + l15) * BK + c8s];
            #pragma unroll
            for (int i = 0; i < NI; ++i)
                #pragma unroll
                for (int j = 0; j < NJ; ++j)
                    acc[i][j] = __builtin_amdgcn_mfma_f32_16x16x32_bf16(af[i], bfv[j], acc[i][j], 0, 0, 0);
        }
        __syncthreads();
    }

    if constexpr (MODE == 1 || MODE == 3) {
        int isf32 = flag[0];
        float bz[NJ];
        #pragma unroll
        for (int j = 0; j < NJ; ++j)
            bz[j] = ldin(bias, b1_e + (size_t)(bn + wn * (NJ * 16) + j * 16 + l15), isf32);
        #pragma unroll
        for (int i = 0; i < NI; ++i) {
            #pragma unroll
            for (int r = 0; r < 4; ++r) {
                int m = bm + wm * (NI * 16) + i * 16 + l4 * 4 + r;
                float cf;
                if constexpr (MODE == 3) {
                    int token = tl[m];
                    cf = coef[(size_t)token * 8 + joff];
                } else {
                    cf = coef[(size_t)m * 8];
                }
                #pragma unroll
                for (int j = 0; j < NJ; ++j) {
                    float v = acc[i][j][r] + bz[j];
                    v = fmaxf(v, 0.f) * cf;
                    obf[(size_t)m * N + bn + wn * (NJ * 16) + j * 16 + l15] = (bf16_t)v;
                }
            }
        }
    } else {
        #pragma unroll
        for (int i = 0; i < NI; ++i) {
            #pragma unroll
            for (int r = 0; r < 4; ++r) {
                int m = bm + wm * (NI * 16) + i * 16 + l4 * 4 + r;
                float* orow;
                if constexpr (MODE == 4) {
                    int token = tl[m];   // sentinel Tn -> dummy row (discarded)
                    orow = oacc + (size_t)token * N + bn + wn * (NJ * 16) + l15;
                } else {
                    orow = oacc + (size_t)m * N + bn + wn * (NJ * 16) + l15;
                }
                #pragma unroll
                for (int j = 0; j < NJ; ++j)
                    orow[j * 16] += acc[i][j][r];
            }
        }
    }
}

// Named wrappers (distinct rocprof kernel names per phase)
__launch_bounds__(256, 2)
__global__ void gemm_sh1_kernel(const bf16_t* __restrict__ A, const bf16_t* __restrict__ Bt,
                                int M, int N, int K, const void* __restrict__ bias, size_t b1_e,
                                const int* __restrict__ flag, const float* __restrict__ coef,
                                bf16_t* __restrict__ obf) {
    gemm_body<1, 128, 128>(A, Bt, M, N, K, bias, b1_e, flag, coef, obf, nullptr, nullptr, nullptr, 0, 0);
}
__launch_bounds__(256, 2)
__global__ void gemm_sh2_kernel(const bf16_t* __restrict__ A, const bf16_t* __restrict__ Bt,
                                int M, int N, int K, float* __restrict__ oacc) {
    gemm_body<2, 128, 128>(A, Bt, M, N, K, nullptr, 0, nullptr, nullptr, nullptr, oacc, nullptr, nullptr, 0, 0);
}
__launch_bounds__(256, 2)
__global__ void gemm_rt1_kernel(const bf16_t* __restrict__ A, const bf16_t* __restrict__ Bt,
                                int M, int N, int K, const void* __restrict__ bias, size_t b1_e,
                                const int* __restrict__ flag, const float* __restrict__ coef,
                                bf16_t* __restrict__ obf, const int* __restrict__ tl,
                                const int* __restrict__ cntp, int tok0, int joff) {
    gemm_body<3, 128, 128>(A, Bt, M, N, K, bias, b1_e, flag, coef, obf, nullptr, tl, cntp, tok0, joff);
}
__launch_bounds__(256, 2)
__global__ void gemm_rt2_kernel(const bf16_t* __restrict__ A, const bf16_t* __restrict__ Bt,
                                int M, int N, int K, float* __restrict__ oacc,
                                const int* __restrict__ tl, const int* __restrict__ cntp, int tok0) {
    gemm_body<4, 64, 128>(A, Bt, M, N, K, nullptr, 0, nullptr, nullptr, nullptr, oacc, tl, cntp, tok0, 0);
}

// ---------------- launcher ----------------
extern "C" void kernel_launch(void* const* d_in, const int* in_sizes, int n_in,
                              void* d_out, int out_size, void* d_ws, size_t ws_size,
                              hipStream_t stream) {
    const void* x      = d_in[0];
    const void* gate_w = d_in[1];
    const void* gate_b = d_in[2];
    const void* sw1    = d_in[3];
    const void* sb1    = d_in[4];
    const void* sw2    = d_in[5];
    const void* sb2    = d_in[6];
    const void* rw1    = d_in[7];
    const void* rb1    = d_in[8];
    const void* rw2    = d_in[9];
    const void* rb2    = d_in[10];

    char* ws = (char*)d_ws;
    int* flag = (int*)ws;
    size_t off = 256;
    bf16_t* W1T = (bf16_t*)(ws + off); off += (size_t)Ff * Dd * sizeof(bf16_t);       // 8 MB
    bf16_t* W2T = (bf16_t*)(ws + off); off += (size_t)Oo * Ff * sizeof(bf16_t);       // 8 MB
    bf16_t* xb  = (bf16_t*)(ws + off); off += (size_t)Tn * Dd * sizeof(bf16_t);       // 16 MB
    bf16_t* xg  = (bf16_t*)(ws + off); off += (size_t)Tn * Dd * sizeof(bf16_t);       // 16 MB
    float* coef = (float*)(ws + off);  off += (size_t)(Tn + 1) * 8 * sizeof(float);   // +sentinel
    off = (off + 255) & ~(size_t)255;
    int* sel    = (int*)(ws + off);    off += (size_t)Tn * sizeof(int);                // 32 KB
    off = (off + 255) & ~(size_t)255;
    int* cntp   = (int*)(ws + off);    off += 256;                                     // cntp[4]
    int* tlist  = (int*)(ws + off);    off += (size_t)4 * Tn * sizeof(int);            // 128 KB
    off = (off + 255) & ~(size_t)255;
    float* accb = (float*)(ws + off);  off += (size_t)(Tn + 1) * Oo * sizeof(float);   // +dummy row
    off = (off + 255) & ~(size_t)255;
    bf16_t* Hs  = (bf16_t*)(ws + off);
    size_t rem = (ws_size > off) ? (ws_size - off) : 0;
    long tcap = (long)(rem / ((size_t)Ff * sizeof(bf16_t)));
    int Tc = (int)((tcap / 128) * 128);
    if (Tc < 128) Tc = 128;
    if (Tc > Tn) Tc = Tn;

    detect_kernel<<<1, 256, 0, stream>>>((const unsigned int*)x, flag);
    gate_fused_kernel<<<Tn, 256, 0, stream>>>(x, gate_w, gate_b, flag, xb, coef, sel);
    build_lists_kernel<<<4, 256, 0, stream>>>(sel, cntp, tlist, coef);
    init_acc_kernel<<<(Tn * Oo) / 256, 256, 0, stream>>>(coef, sb2, rb2, flag, accb);

    // ---- shared experts: dense (coef = 0.5 each) ----
    for (int j = 0; j < 2; ++j) {
        size_t w1_e = (size_t)j * Dd * Ff;
        size_t w2_e = (size_t)j * Ff * Oo;
        size_t b1_e = (size_t)j * Ff;
        transpose_kernel<<<dim3(Ff / 64, Dd / 64), 256, 0, stream>>>(sw1, w1_e, flag, W1T, Dd, Ff);
        transpose_kernel<<<dim3(Oo / 64, Ff / 64), 256, 0, stream>>>(sw2, w2_e, flag, W2T, Ff, Oo);
        for (int tok0 = 0; tok0 < Tn; tok0 += Tc) {
            int tc = (Tn - tok0 < Tc) ? (Tn - tok0) : Tc;
            gemm_sh1_kernel<<<dim3(tc / 128, Ff / 128), 256, 0, stream>>>(
                xb + (size_t)tok0 * Dd, W1T, tc, Ff, Dd,
                sb1, b1_e, flag, coef + (size_t)tok0 * 8 + j, Hs);
            gemm_sh2_kernel<<<dim3(tc / 128, Oo / 128), 256, 0, stream>>>(
                Hs, W2T, tc, Oo, Ff, accb + (size_t)tok0 * Oo);
        }
    }

    // ---- routed experts: compacted token lists ----
    for (int e = 0; e < 4; ++e) {
        size_t w1_e = (size_t)e * Dd * Ff;
        size_t w2_e = (size_t)e * Ff * Oo;
        size_t b1_e = (size_t)e * Ff;
        transpose_kernel<<<dim3(Ff / 64, Dd / 64), 256, 0, stream>>>(rw1, w1_e, flag, W1T, Dd, Ff);
        transpose_kernel<<<dim3(Oo / 64, Ff / 64), 256, 0, stream>>>(rw2, w2_e, flag, W2T, Ff, Oo);
        gather_kernel<<<Tn / 2, 256, 0, stream>>>(xb, tlist + (size_t)e * Tn, cntp + e, xg);
        for (int tok0 = 0; tok0 < Tn; tok0 += Tc) {
            int tc = (Tn - tok0 < Tc) ? (Tn - tok0) : Tc;
            // worst-case grids; blocks past cntp[e]-tok0 exit immediately
            gemm_rt1_kernel<<<dim3(tc / 128, Ff / 128), 256, 0, stream>>>(
                xg + (size_t)tok0 * Dd, W1T, tc, Ff, Dd,
                rb1, b1_e, flag, coef, Hs,
                tlist + (size_t)e * Tn + tok0, cntp + e, tok0, 2 + e);
            gemm_rt2_kernel<<<dim3(tc / 64, Oo / 128), 256, 0, stream>>>(
                Hs, W2T, tc, Oo, Ff, accb,
                tlist + (size_t)e * Tn + tok0, cntp + e, tok0);
        }
    }

    convert_kernel<<<(Tn * Oo) / 256, 256, 0, stream>>>(accb, flag, d_out);
}